// Round 4
// baseline (463.988 us; speedup 1.0000x reference)
//
#include <hip/hip_runtime.h>

typedef short bf16x8 __attribute__((ext_vector_type(8)));
typedef short bf16x4 __attribute__((ext_vector_type(4)));
typedef float f32x4 __attribute__((ext_vector_type(4)));
typedef float f32x2 __attribute__((ext_vector_type(2)));

#define PS 32        // nodes per partition
#define PMAX 4096    // max partitions supported (N <= 131072)
#define CAPP 1312    // region capacity: Poisson(1024) + 9 sigma
#define NB 256       // scat blocks (1024 threads each)

__device__ __forceinline__ unsigned short f2bf(float f) {
    unsigned int u = __float_as_uint(f);
    u = (u + 0x7FFFu + ((u >> 16) & 1u)) >> 16;
    return (unsigned short)u;
}

// ---- scat: fused histogram + scatter into fixed-capacity partition regions ----
// Round-4: also accumulates deg[dst] via global f32 atomics (memory-side),
// which deletes dgemm1's whole degree pass (33MB regions re-read + 6.4M LDS
// atomics at 1.5 blocks/CU). First 12 blocks pre-convert weights to bf16.
__global__ __launch_bounds__(1024) void scat_k(const int* __restrict__ ei,
                                               const float* __restrict__ ew,
                                               int* __restrict__ partCnt,
                                               float* __restrict__ deg,
                                               int2* __restrict__ regions,
                                               const float* __restrict__ Wc,
                                               const float* __restrict__ Wf,
                                               const float* __restrict__ W2,
                                               unsigned short* __restrict__ wcb,
                                               unsigned short* __restrict__ wfb,
                                               unsigned short* __restrict__ w2b,
                                               int E, int P, int EPB) {
    __shared__ int cntl[PMAX];
    __shared__ int basel[PMAX];
    const int b = blockIdx.x, tid = threadIdx.x;

    if (b < 12) {  // weight prep: 12288 float4 chunks = 3 x 16384 elems
        int t = (b << 10) | tid;
        int a = t >> 12, idx = t & 4095;
        const float4* s4 = (const float4*)(a == 0 ? Wc : (a == 1 ? Wf : W2));
        unsigned short* dw = (a == 0 ? wcb : (a == 1 ? wfb : w2b));
        float4 v = s4[idx];
        ushort4 o;
        o.x = f2bf(v.x); o.y = f2bf(v.y); o.z = f2bf(v.z); o.w = f2bf(v.w);
        *(ushort4*)(dw + idx * 4) = o;
    }

    for (int i = tid; i < P; i += 1024) cntl[i] = 0;
    __syncthreads();
    const int s = b * EPB, e = min(E, s + EPB);
    for (int i = s + tid; i < e; i += 1024)
        atomicAdd(&cntl[ei[E + i] >> 5], 1);
    __syncthreads();
    for (int p = tid; p < P; p += 1024) {
        int c = cntl[p];
        basel[p] = p * CAPP + (c ? atomicAdd(&partCnt[p], c) : 0);
        cntl[p] = 0;
    }
    __syncthreads();
    for (int i = s + tid; i < e; i += 1024) {
        int src = ei[i];          // cold read
        int dst = ei[E + i];      // L2-hot (read in phase 1)
        float w = ew[i];
        int p = dst >> 5, dl = dst & 31;
        atomicAdd(&deg[dst], w);  // weighted in-degree (self-loop added later)
        int lidx = atomicAdd(&cntl[p], 1);
        int pos = basel[p] + lidx;
        if (pos < (p + 1) * CAPP)  // overflow guard: statistically never
            regions[pos] = make_int2(src | (dl << 24), __float_as_int(w));
    }
}

// ---- dgemm1: dinv = rsqrt(1+deg); h' = bf16(x@Wc^T)  (UNSCALED now) ----
// Pure GEMM: no regions read, no LDS atomics, no scan (all deleted in round 4).
// h' stored CHANNEL-SPLIT: h[2][N][64] (128B = one cache line per node-half).
__global__ __launch_bounds__(256) void dgemm1_k(const float* __restrict__ x,
                                                const unsigned short* __restrict__ Wcb,
                                                const float* __restrict__ deg,
                                                float* __restrict__ dinv,
                                                unsigned short* __restrict__ h,
                                                int M) {
    __shared__ __align__(16) unsigned short Wl[128 * 136];
    const int tid = threadIdx.x;

    {   // dinv for this block's 256 nodes
        int node = blockIdx.x * 256 + tid;
        if (node < M) dinv[node] = rsqrtf(1.0f + deg[node]);
    }

    // stage Wcb (bf16 dense) -> Wl (136-stride); no conversion
#pragma unroll
    for (int i = 0; i < 8; ++i) {
        int c = i * 256 + tid;
        int r = c >> 4, col = (c & 15) * 8;
        *(bf16x8*)&Wl[r * 136 + col] = *(const bf16x8*)(Wcb + c * 8);
    }
    __syncthreads();

    const int wave = tid >> 6, lane = tid & 63;
    const int m = lane & 15, quad = lane >> 4;

#pragma unroll
    for (int t = 0; t < 4; ++t) {
        const int tileBase = blockIdx.x * 256 + t * 64;
        if (tileBase >= M) break;
        const int rowBase = tileBase + wave * 16;
        int arow = rowBase + m;
        int arowc = arow < M ? arow : (M - 1);

        bf16x8 afrag[4];
        const float* pa = x + (size_t)arowc * 128 + quad * 8;
#pragma unroll
        for (int kc = 0; kc < 4; ++kc) {
            float4 v0 = *(const float4*)(pa + kc * 32);
            float4 v1 = *(const float4*)(pa + kc * 32 + 4);
            bf16x8 f;
            f[0] = (short)f2bf(v0.x); f[1] = (short)f2bf(v0.y);
            f[2] = (short)f2bf(v0.z); f[3] = (short)f2bf(v0.w);
            f[4] = (short)f2bf(v1.x); f[5] = (short)f2bf(v1.y);
            f[6] = (short)f2bf(v1.z); f[7] = (short)f2bf(v1.w);
            afrag[kc] = f;
        }

#pragma unroll
        for (int nt = 0; nt < 8; ++nt) {
            f32x4 acc = {0.f, 0.f, 0.f, 0.f};
            const unsigned short* wb = &Wl[(nt * 16 + m) * 136 + quad * 8];
#pragma unroll
            for (int kc = 0; kc < 4; ++kc) {
                bf16x8 bfrag = *(const bf16x8*)(wb + kc * 32);
                acc = __builtin_amdgcn_mfma_f32_16x16x32_bf16(afrag[kc], bfrag, acc, 0, 0, 0);
            }
            const int col = nt * 16 + m;
#pragma unroll
            for (int r = 0; r < 4; ++r) {
                int row = rowBase + quad * 4 + r;
                if (row < M)  // channel-split store: h[col>>6][row][col&63]
                    h[((size_t)(col >> 6) * M + row) * 64 + (col & 63)] = f2bf(acc[r]);
            }
        }
    }
}

// ---- aggF: register-staged counting sort + per-node gather-reduce ----
// h2[n] = bf16(relu( dinv[n]*sum(w*dinv[src]*h[src]) + dinv[n]^2*h[n] + b_conv ))
// Round-4 sort: key = (node, src>>14) -> each node's edges are src-chunk-ordered.
// All concurrent blocks progress at similar speed => chip-wide instantaneous
// gather working set ~ one 2.1MB chunk slice (fits 4MB/XCD L2), no inner-loop
// change. dinv[src] (400KB, L2-resident) folded into stag weight at sort time.
__global__ __launch_bounds__(256) void aggF_k(const int* __restrict__ partCnt,
                                              const int2* __restrict__ regions,
                                              const unsigned short* __restrict__ h,
                                              const float* __restrict__ dinv,
                                              const float* __restrict__ bconv,
                                              unsigned short* __restrict__ h2, int N) {
    __shared__ __align__(16) int2 stag[CAPP];
    __shared__ int c256[256];          // (node,chunk) hist -> offsets -> cursors
    __shared__ int cstart[PS + 1];
    const int p = blockIdx.x, tid = threadIdx.x;
    const int cnt = min(partCnt[p], CAPP);
    const int2* reg = regions + (size_t)p * CAPP;

    c256[tid] = 0;
    __syncthreads();

    // load region entries into registers (<=6/thread), hist, prefetch dinv[src]
    int2 rr[6]; float dvv[6]; int key[6]; bool okk[6];
#pragma unroll
    for (int k = 0; k < 6; ++k) {
        int i = tid + k * 256;
        okk[k] = (i < cnt);
        rr[k] = okk[k] ? reg[i] : make_int2(0, 0);
        dvv[k] = okk[k] ? dinv[rr[k].x & 0xFFFFFF] : 0.f;
        key[k] = (((rr[k].x >> 24) & 31) << 3) | ((rr[k].x & 0xFFFFFF) >> 14);
        if (okk[k]) atomicAdd(&c256[key[k]], 1);
    }
    __syncthreads();
    if (tid < PS) {  // threads 0..31 = lanes 0..31 of wave 0
        int s = 0;
#pragma unroll
        for (int c = 0; c < 8; ++c) s += c256[tid * 8 + c];
        int v = s;
#pragma unroll
        for (int off = 1; off < 32; off <<= 1) {
            int u = __shfl_up(v, off, 32);
            if (tid >= off) v += u;
        }
        cstart[tid] = v - s;
        if (tid == PS - 1) cstart[PS] = v;
        int run = v - s;
#pragma unroll
        for (int c = 0; c < 8; ++c) { int t2 = c256[tid * 8 + c]; c256[tid * 8 + c] = run; run += t2; }
    }
    __syncthreads();
    // placement: pre-shifted byte offset + dinv[src]-folded weight
#pragma unroll
    for (int k = 0; k < 6; ++k) {
        if (okk[k]) {
            int pos = atomicAdd(&c256[key[k]], 1);
            stag[pos] = make_int2((rr[k].x & 0xFFFFFF) << 7,
                                  __float_as_int(__int_as_float(rr[k].y) * dvv[k]));
        }
    }
    __syncthreads();

    const int wave = tid >> 6, lane = tid & 63;
    const int g = lane >> 4;              // edge slot 0..3
    const int c4 = (lane & 15) * 4;       // channel base within the 64-ch half
    const int c4b = c4 * 2;               // ...as bytes

#define ACC2(q, w) {                                                        \
        unsigned ux = (unsigned)(q).x, uy = (unsigned)(q).y;                \
        f32x2 ww; ww[0] = (w); ww[1] = (w);                                 \
        f32x2 v01, v23;                                                     \
        v01[0] = __uint_as_float(ux << 16);                                 \
        v01[1] = __uint_as_float(ux & 0xFFFF0000u);                         \
        v23[0] = __uint_as_float(uy << 16);                                 \
        v23[1] = __uint_as_float(uy & 0xFFFF0000u);                         \
        a01 = v01 * ww + a01; a23 = v23 * ww + a23; }

#pragma unroll
    for (int hh = 0; hh < 2; ++hh) {
        const char* hb = (const char*)h + ((size_t)hh * (size_t)N << 7);
        for (int nl = wave; nl < PS; nl += 4) {
            int n = p * PS + nl;
            if (n >= N) continue;
            const int s = cstart[nl], e = cstart[nl + 1];
            f32x2 a01 = {0.f, 0.f}, a23 = {0.f, 0.f};
            int j = s;
            const int e32 = s + ((e - s) & ~31);
            for (; j < e32; j += 32) {
                int2 r0 = stag[j + g];
                int2 r1 = stag[j + 4 + g];
                int2 r2 = stag[j + 8 + g];
                int2 r3 = stag[j + 12 + g];
                int2 r4 = stag[j + 16 + g];
                int2 r5 = stag[j + 20 + g];
                int2 r6 = stag[j + 24 + g];
                int2 r7 = stag[j + 28 + g];
                int2 q0 = *(const int2*)(hb + ((unsigned)r0.x + c4b));
                int2 q1 = *(const int2*)(hb + ((unsigned)r1.x + c4b));
                int2 q2 = *(const int2*)(hb + ((unsigned)r2.x + c4b));
                int2 q3 = *(const int2*)(hb + ((unsigned)r3.x + c4b));
                int2 q4 = *(const int2*)(hb + ((unsigned)r4.x + c4b));
                int2 q5 = *(const int2*)(hb + ((unsigned)r5.x + c4b));
                int2 q6 = *(const int2*)(hb + ((unsigned)r6.x + c4b));
                int2 q7 = *(const int2*)(hb + ((unsigned)r7.x + c4b));
                ACC2(q0, __int_as_float(r0.y));
                ACC2(q1, __int_as_float(r1.y));
                ACC2(q2, __int_as_float(r2.y));
                ACC2(q3, __int_as_float(r3.y));
                ACC2(q4, __int_as_float(r4.y));
                ACC2(q5, __int_as_float(r5.y));
                ACC2(q6, __int_as_float(r6.y));
                ACC2(q7, __int_as_float(r7.y));
            }
            const int e16 = s + ((e - s) & ~15);
            for (; j < e16; j += 16) {
                int2 r0 = stag[j + g];
                int2 r1 = stag[j + 4 + g];
                int2 r2 = stag[j + 8 + g];
                int2 r3 = stag[j + 12 + g];
                int2 q0 = *(const int2*)(hb + ((unsigned)r0.x + c4b));
                int2 q1 = *(const int2*)(hb + ((unsigned)r1.x + c4b));
                int2 q2 = *(const int2*)(hb + ((unsigned)r2.x + c4b));
                int2 q3 = *(const int2*)(hb + ((unsigned)r3.x + c4b));
                ACC2(q0, __int_as_float(r0.y));
                ACC2(q1, __int_as_float(r1.y));
                ACC2(q2, __int_as_float(r2.y));
                ACC2(q3, __int_as_float(r3.y));
            }
            for (; j < e; j += 8) {
                int j0 = j + g, j1 = j + 4 + g;
                int2 r0 = stag[j0 < e ? j0 : s];
                int2 r1 = stag[j1 < e ? j1 : s];
                float w0 = (j0 < e) ? __int_as_float(r0.y) : 0.f;
                float w1 = (j1 < e) ? __int_as_float(r1.y) : 0.f;
                int2 q0 = *(const int2*)(hb + ((unsigned)r0.x + c4b));
                int2 q1 = *(const int2*)(hb + ((unsigned)r1.x + c4b));
                ACC2(q0, w0);
                ACC2(q1, w1);
            }
            float acc[4] = {a01[0], a01[1], a23[0], a23[1]};
#pragma unroll
            for (int k = 0; k < 4; ++k) {
                float v = acc[k];
                v += __shfl_xor(v, 16, 64);
                v += __shfl_xor(v, 32, 64);
                acc[k] = v;
            }
            if (g == 0) {
                float di = dinv[n];
                float sc = di * di;  // self-loop: dinv[n]*1*dinv[n]*h[n]
                int2 qs = *(const int2*)(hb + (((size_t)(unsigned)n << 7) + c4b));
                float4 b = *(const float4*)(bconv + hh * 64 + c4);
                unsigned ux = (unsigned)qs.x, uy = (unsigned)qs.y;
                bf16x4 o;
                o[0] = (short)f2bf(fmaxf(di * acc[0] + sc * __uint_as_float(ux << 16) + b.x, 0.f));
                o[1] = (short)f2bf(fmaxf(di * acc[1] + sc * __uint_as_float(ux & 0xFFFF0000u) + b.y, 0.f));
                o[2] = (short)f2bf(fmaxf(di * acc[2] + sc * __uint_as_float(uy << 16) + b.z, 0.f));
                o[3] = (short)f2bf(fmaxf(di * acc[3] + sc * __uint_as_float(uy & 0xFFFF0000u) + b.w, 0.f));
                *(bf16x4*)(h2 + (size_t)n * 128 + hh * 64 + c4) = o;
            }
        }
    }
#undef ACC2
}

// ---- gemm23: out = relu(h2 @ Wf^T + bf) @ W2^T + b2, intermediate staged in LDS ----
__global__ __launch_bounds__(256) void gemm23_k(const unsigned short* __restrict__ h2,
                                                const unsigned short* __restrict__ Wfb,
                                                const float* __restrict__ bfc,
                                                const unsigned short* __restrict__ W2b,
                                                const float* __restrict__ b2,
                                                float* __restrict__ out, int M) {
    __shared__ __align__(16) unsigned short Wl[128 * 136];
    __shared__ __align__(16) unsigned short Tl[64 * 136];
    const int tid = threadIdx.x;

    // stage Wfb (bf16 dense) -> Wl (136-stride)
#pragma unroll
    for (int i = 0; i < 8; ++i) {
        int c = i * 256 + tid;
        int r = c >> 4, col = (c & 15) * 8;
        *(bf16x8*)&Wl[r * 136 + col] = *(const bf16x8*)(Wfb + c * 8);
    }
    __syncthreads();

    const int wave = tid >> 6, lane = tid & 63;
    const int m = lane & 15, quad = lane >> 4;
    const int rowBase = blockIdx.x * 64 + wave * 16;
    int arow = rowBase + m;
    int arowc = arow < M ? arow : (M - 1);

    bf16x8 afrag[4];
    {
        const unsigned short* pa = h2 + (size_t)arowc * 128 + quad * 8;
#pragma unroll
        for (int kc = 0; kc < 4; ++kc)
            afrag[kc] = *(const bf16x8*)(pa + kc * 32);
    }

    // stage 1: T = bf16(relu(h2 @ Wf^T + bf)) -> LDS
#pragma unroll
    for (int nt = 0; nt < 8; ++nt) {
        f32x4 acc = {0.f, 0.f, 0.f, 0.f};
        const unsigned short* wb = &Wl[(nt * 16 + m) * 136 + quad * 8];
#pragma unroll
        for (int kc = 0; kc < 4; ++kc) {
            bf16x8 bfrag = *(const bf16x8*)(wb + kc * 32);
            acc = __builtin_amdgcn_mfma_f32_16x16x32_bf16(afrag[kc], bfrag, acc, 0, 0, 0);
        }
        const int col = nt * 16 + m;
        float bv = bfc[col];
#pragma unroll
        for (int r = 0; r < 4; ++r) {
            int rowl = wave * 16 + quad * 4 + r;
            Tl[rowl * 136 + col] = f2bf(fmaxf(acc[r] + bv, 0.f));
        }
    }
    __syncthreads();

    // stage W2b (overwrite Wl)
#pragma unroll
    for (int i = 0; i < 8; ++i) {
        int c = i * 256 + tid;
        int r = c >> 4, col = (c & 15) * 8;
        *(bf16x8*)&Wl[r * 136 + col] = *(const bf16x8*)(W2b + c * 8);
    }
    __syncthreads();

    // stage 2: out = T @ W2^T + b2
    bf16x8 afrag2[4];
    {
        const unsigned short* pa = &Tl[(wave * 16 + m) * 136 + quad * 8];
#pragma unroll
        for (int kc = 0; kc < 4; ++kc)
            afrag2[kc] = *(const bf16x8*)(pa + kc * 32);
    }
#pragma unroll
    for (int nt = 0; nt < 8; ++nt) {
        f32x4 acc = {0.f, 0.f, 0.f, 0.f};
        const unsigned short* wb = &Wl[(nt * 16 + m) * 136 + quad * 8];
#pragma unroll
        for (int kc = 0; kc < 4; ++kc) {
            bf16x8 bfrag = *(const bf16x8*)(wb + kc * 32);
            acc = __builtin_amdgcn_mfma_f32_16x16x32_bf16(afrag2[kc], bfrag, acc, 0, 0, 0);
        }
        const int col = nt * 16 + m;
        float bv = b2[col];
#pragma unroll
        for (int r = 0; r < 4; ++r) {
            int row = rowBase + quad * 4 + r;
            if (row < M)
                out[(size_t)row * 128 + col] = acc[r] + bv;
        }
    }
}

extern "C" void kernel_launch(void* const* d_in, const int* in_sizes, int n_in,
                              void* d_out, int out_size, void* d_ws, size_t ws_size,
                              hipStream_t stream) {
    const float* x  = (const float*)d_in[0];
    const int* ei   = (const int*)d_in[1];
    const float* ew = (const float*)d_in[2];
    const float* Wc = (const float*)d_in[3];
    const float* bc = (const float*)d_in[4];
    const float* Wf = (const float*)d_in[5];
    const float* bf = (const float*)d_in[6];
    const float* W2 = (const float*)d_in[7];
    const float* b2 = (const float*)d_in[8];
    float* out = (float*)d_out;

    const int N = in_sizes[0] / 128;
    const int E = in_sizes[2];
    const int P = (N + PS - 1) / PS;  // 3125

    auto align256 = [](size_t v) { return (v + 255) & ~(size_t)255; };
    char* ws = (char*)d_ws;
    size_t off = 0;
    float* dinv  = (float*)(ws + off); off += align256((size_t)N * 4);
    int* partCnt = (int*)(ws + off);   off += align256((size_t)P * 4);
    float* deg   = (float*)(ws + off); off += align256((size_t)N * 4);
    unsigned short* wcb = (unsigned short*)(ws + off); off += align256(16384 * 2);
    unsigned short* wfb = (unsigned short*)(ws + off); off += align256(16384 * 2);
    unsigned short* w2b = (unsigned short*)(ws + off); off += align256(16384 * 2);
    unsigned short* h  = (unsigned short*)(ws + off); off += (size_t)N * 256;  // h'[2][N][64] channel-split
    unsigned short* h2 = (unsigned short*)(ws + off);

    // d_out scratch: partition regions P*CAPP*8B = 32.8MB <= 51.2MB,
    // consumed by aggF before gemm23 rewrites d_out.
    int2* regions = (int2*)out;

    const int EPB = (E + NB - 1) / NB;

    // zero partCnt + deg in one contiguous memset
    hipMemsetAsync(partCnt, 0, align256((size_t)P * 4) + (size_t)N * 4, stream);
    scat_k<<<NB, 1024, 0, stream>>>(ei, ew, partCnt, deg, regions, Wc, Wf, W2, wcb, wfb, w2b, E, P, EPB);
    dgemm1_k<<<(N + 255) / 256, 256, 0, stream>>>(x, wcb, deg, dinv, h, N);
    aggF_k<<<P, 256, 0, stream>>>(partCnt, regions, h, dinv, bc, h2, N);
    gemm23_k<<<(N + 63) / 64, 256, 0, stream>>>(h2, wfb, bf, w2b, b2, out, N);
}

// Round 5
// 383.470 us; speedup vs baseline: 1.2100x; 1.2100x over previous
//
#include <hip/hip_runtime.h>

typedef short bf16x8 __attribute__((ext_vector_type(8)));
typedef short bf16x4 __attribute__((ext_vector_type(4)));
typedef float f32x4 __attribute__((ext_vector_type(4)));
typedef float f32x2 __attribute__((ext_vector_type(2)));

#define PS 32        // nodes per partition
#define PMAX 4096    // max partitions supported (N <= 131072)
#define CAPP 1312    // region capacity: Poisson(1024) + 9 sigma
#define NB 256       // scat blocks (1024 threads each)

__device__ __forceinline__ unsigned short f2bf(float f) {
    unsigned int u = __float_as_uint(f);
    u = (u + 0x7FFFu + ((u >> 16) & 1u)) >> 16;
    return (unsigned short)u;
}

// ---- scat: fused histogram + scatter into fixed-capacity partition regions ----
// Round-5: REVERTED the per-edge global deg atomic (round-4 showed it costs
// 3.2M x 64B = 204MB of coherent-write traffic, +105us on scat). deg is now
// recovered from the regions by deg_k. First 12 blocks pre-convert weights.
__global__ __launch_bounds__(1024) void scat_k(const int* __restrict__ ei,
                                               const float* __restrict__ ew,
                                               int* __restrict__ partCnt,
                                               int2* __restrict__ regions,
                                               const float* __restrict__ Wc,
                                               const float* __restrict__ Wf,
                                               const float* __restrict__ W2,
                                               unsigned short* __restrict__ wcb,
                                               unsigned short* __restrict__ wfb,
                                               unsigned short* __restrict__ w2b,
                                               int E, int P, int EPB) {
    __shared__ int cntl[PMAX];
    __shared__ int basel[PMAX];
    const int b = blockIdx.x, tid = threadIdx.x;

    if (b < 12) {  // weight prep: 12288 float4 chunks = 3 x 16384 elems
        int t = (b << 10) | tid;
        int a = t >> 12, idx = t & 4095;
        const float4* s4 = (const float4*)(a == 0 ? Wc : (a == 1 ? Wf : W2));
        unsigned short* dw = (a == 0 ? wcb : (a == 1 ? wfb : w2b));
        float4 v = s4[idx];
        ushort4 o;
        o.x = f2bf(v.x); o.y = f2bf(v.y); o.z = f2bf(v.z); o.w = f2bf(v.w);
        *(ushort4*)(dw + idx * 4) = o;
    }

    for (int i = tid; i < P; i += 1024) cntl[i] = 0;
    __syncthreads();
    const int s = b * EPB, e = min(E, s + EPB);
    for (int i = s + tid; i < e; i += 1024)
        atomicAdd(&cntl[ei[E + i] >> 5], 1);
    __syncthreads();
    for (int p = tid; p < P; p += 1024) {
        int c = cntl[p];
        basel[p] = p * CAPP + (c ? atomicAdd(&partCnt[p], c) : 0);
        cntl[p] = 0;
    }
    __syncthreads();
    for (int i = s + tid; i < e; i += 1024) {
        int src = ei[i];          // cold read
        int dst = ei[E + i];      // L2-hot (read in phase 1)
        float w = ew[i];
        int p = dst >> 5, dl = dst & 31;
        int lidx = atomicAdd(&cntl[p], 1);
        int pos = basel[p] + lidx;
        if (pos < (p + 1) * CAPP)  // overflow guard: statistically never
            regions[pos] = make_int2(src | (dl << 24), __float_as_int(w));
    }
}

// ---- deg_k: per-partition weighted in-degree from regions -> dinv ----
// One partition per block: coalesced read of ~1024 entries (26MB total chip-wide,
// ~6us), 32-counter LDS accumulate, dinv = rsqrt(1+deg). Replaces round-4's
// per-edge global atomics AND round-3's degree pass inside dgemm1.
__global__ __launch_bounds__(256) void deg_k(const int* __restrict__ partCnt,
                                             const int2* __restrict__ regions,
                                             float* __restrict__ dinv, int N) {
    __shared__ float degl[PS];
    const int p = blockIdx.x, tid = threadIdx.x;
    if (tid < PS) degl[tid] = 0.f;
    __syncthreads();
    const int cnt = min(partCnt[p], CAPP);
    const int2* reg = regions + (size_t)p * CAPP;
    for (int i = tid; i < cnt; i += 256) {
        int2 r = reg[i];
        atomicAdd(&degl[(r.x >> 24) & 31], __int_as_float(r.y));
    }
    __syncthreads();
    if (tid < PS) {
        int n = p * PS + tid;
        if (n < N) dinv[n] = rsqrtf(1.0f + degl[tid]);  // self-loop weight 1
    }
}

// ---- dgemm1: pure GEMM h' = bf16(x@Wc^T), UNSCALED, channel-split store ----
__global__ __launch_bounds__(256) void dgemm1_k(const float* __restrict__ x,
                                                const unsigned short* __restrict__ Wcb,
                                                unsigned short* __restrict__ h,
                                                int M) {
    __shared__ __align__(16) unsigned short Wl[128 * 136];
    const int tid = threadIdx.x;

    // stage Wcb (bf16 dense) -> Wl (136-stride); no conversion
#pragma unroll
    for (int i = 0; i < 8; ++i) {
        int c = i * 256 + tid;
        int r = c >> 4, col = (c & 15) * 8;
        *(bf16x8*)&Wl[r * 136 + col] = *(const bf16x8*)(Wcb + c * 8);
    }
    __syncthreads();

    const int wave = tid >> 6, lane = tid & 63;
    const int m = lane & 15, quad = lane >> 4;

#pragma unroll
    for (int t = 0; t < 4; ++t) {
        const int tileBase = blockIdx.x * 256 + t * 64;
        if (tileBase >= M) break;
        const int rowBase = tileBase + wave * 16;
        int arow = rowBase + m;
        int arowc = arow < M ? arow : (M - 1);

        bf16x8 afrag[4];
        const float* pa = x + (size_t)arowc * 128 + quad * 8;
#pragma unroll
        for (int kc = 0; kc < 4; ++kc) {
            float4 v0 = *(const float4*)(pa + kc * 32);
            float4 v1 = *(const float4*)(pa + kc * 32 + 4);
            bf16x8 f;
            f[0] = (short)f2bf(v0.x); f[1] = (short)f2bf(v0.y);
            f[2] = (short)f2bf(v0.z); f[3] = (short)f2bf(v0.w);
            f[4] = (short)f2bf(v1.x); f[5] = (short)f2bf(v1.y);
            f[6] = (short)f2bf(v1.z); f[7] = (short)f2bf(v1.w);
            afrag[kc] = f;
        }

#pragma unroll
        for (int nt = 0; nt < 8; ++nt) {
            f32x4 acc = {0.f, 0.f, 0.f, 0.f};
            const unsigned short* wb = &Wl[(nt * 16 + m) * 136 + quad * 8];
#pragma unroll
            for (int kc = 0; kc < 4; ++kc) {
                bf16x8 bfrag = *(const bf16x8*)(wb + kc * 32);
                acc = __builtin_amdgcn_mfma_f32_16x16x32_bf16(afrag[kc], bfrag, acc, 0, 0, 0);
            }
            const int col = nt * 16 + m;
#pragma unroll
            for (int r = 0; r < 4; ++r) {
                int row = rowBase + quad * 4 + r;
                if (row < M)  // channel-split store: h[col>>6][row][col&63]
                    h[((size_t)(col >> 6) * M + row) * 64 + (col & 63)] = f2bf(acc[r]);
            }
        }
    }
}

// ---- aggF: register-staged counting sort + per-node gather-reduce ----
// h2[n] = bf16(relu( dinv[n]*sum(w*dinv[src]*h[src]) + dinv[n]^2*h[n] + b_conv ))
// Sort key = (node, src>>14): each node's edges are src-chunk-ordered so the
// chip-wide instantaneous gather working set tracks ~one 2.1MB chunk slice.
// dinv[src] (400KB, L2-resident) folded into stag weight at sort time.
__global__ __launch_bounds__(256) void aggF_k(const int* __restrict__ partCnt,
                                              const int2* __restrict__ regions,
                                              const unsigned short* __restrict__ h,
                                              const float* __restrict__ dinv,
                                              const float* __restrict__ bconv,
                                              unsigned short* __restrict__ h2, int N) {
    __shared__ __align__(16) int2 stag[CAPP];
    __shared__ int c256[256];          // (node,chunk) hist -> offsets -> cursors
    __shared__ int cstart[PS + 1];
    const int p = blockIdx.x, tid = threadIdx.x;
    const int cnt = min(partCnt[p], CAPP);
    const int2* reg = regions + (size_t)p * CAPP;

    c256[tid] = 0;
    __syncthreads();

    // load region entries into registers (<=6/thread), hist, prefetch dinv[src]
    int2 rr[6]; float dvv[6]; int key[6]; bool okk[6];
#pragma unroll
    for (int k = 0; k < 6; ++k) {
        int i = tid + k * 256;
        okk[k] = (i < cnt);
        rr[k] = okk[k] ? reg[i] : make_int2(0, 0);
        dvv[k] = okk[k] ? dinv[rr[k].x & 0xFFFFFF] : 0.f;
        key[k] = (((rr[k].x >> 24) & 31) << 3) | ((rr[k].x & 0xFFFFFF) >> 14);
        if (okk[k]) atomicAdd(&c256[key[k]], 1);
    }
    __syncthreads();
    if (tid < PS) {  // threads 0..31 = lanes 0..31 of wave 0
        int s = 0;
#pragma unroll
        for (int c = 0; c < 8; ++c) s += c256[tid * 8 + c];
        int v = s;
#pragma unroll
        for (int off = 1; off < 32; off <<= 1) {
            int u = __shfl_up(v, off, 32);
            if (tid >= off) v += u;
        }
        cstart[tid] = v - s;
        if (tid == PS - 1) cstart[PS] = v;
        int run = v - s;
#pragma unroll
        for (int c = 0; c < 8; ++c) { int t2 = c256[tid * 8 + c]; c256[tid * 8 + c] = run; run += t2; }
    }
    __syncthreads();
    // placement: pre-shifted byte offset + dinv[src]-folded weight
#pragma unroll
    for (int k = 0; k < 6; ++k) {
        if (okk[k]) {
            int pos = atomicAdd(&c256[key[k]], 1);
            stag[pos] = make_int2((rr[k].x & 0xFFFFFF) << 7,
                                  __float_as_int(__int_as_float(rr[k].y) * dvv[k]));
        }
    }
    __syncthreads();

    const int wave = tid >> 6, lane = tid & 63;
    const int g = lane >> 4;              // edge slot 0..3
    const int c4 = (lane & 15) * 4;       // channel base within the 64-ch half
    const int c4b = c4 * 2;               // ...as bytes

#define ACC2(q, w) {                                                        \
        unsigned ux = (unsigned)(q).x, uy = (unsigned)(q).y;                \
        f32x2 ww; ww[0] = (w); ww[1] = (w);                                 \
        f32x2 v01, v23;                                                     \
        v01[0] = __uint_as_float(ux << 16);                                 \
        v01[1] = __uint_as_float(ux & 0xFFFF0000u);                         \
        v23[0] = __uint_as_float(uy << 16);                                 \
        v23[1] = __uint_as_float(uy & 0xFFFF0000u);                         \
        a01 = v01 * ww + a01; a23 = v23 * ww + a23; }

#pragma unroll
    for (int hh = 0; hh < 2; ++hh) {
        const char* hb = (const char*)h + ((size_t)hh * (size_t)N << 7);
        for (int nl = wave; nl < PS; nl += 4) {
            int n = p * PS + nl;
            if (n >= N) continue;
            const int s = cstart[nl], e = cstart[nl + 1];
            f32x2 a01 = {0.f, 0.f}, a23 = {0.f, 0.f};
            int j = s;
            const int e32 = s + ((e - s) & ~31);
            for (; j < e32; j += 32) {
                int2 r0 = stag[j + g];
                int2 r1 = stag[j + 4 + g];
                int2 r2 = stag[j + 8 + g];
                int2 r3 = stag[j + 12 + g];
                int2 r4 = stag[j + 16 + g];
                int2 r5 = stag[j + 20 + g];
                int2 r6 = stag[j + 24 + g];
                int2 r7 = stag[j + 28 + g];
                int2 q0 = *(const int2*)(hb + ((unsigned)r0.x + c4b));
                int2 q1 = *(const int2*)(hb + ((unsigned)r1.x + c4b));
                int2 q2 = *(const int2*)(hb + ((unsigned)r2.x + c4b));
                int2 q3 = *(const int2*)(hb + ((unsigned)r3.x + c4b));
                int2 q4 = *(const int2*)(hb + ((unsigned)r4.x + c4b));
                int2 q5 = *(const int2*)(hb + ((unsigned)r5.x + c4b));
                int2 q6 = *(const int2*)(hb + ((unsigned)r6.x + c4b));
                int2 q7 = *(const int2*)(hb + ((unsigned)r7.x + c4b));
                ACC2(q0, __int_as_float(r0.y));
                ACC2(q1, __int_as_float(r1.y));
                ACC2(q2, __int_as_float(r2.y));
                ACC2(q3, __int_as_float(r3.y));
                ACC2(q4, __int_as_float(r4.y));
                ACC2(q5, __int_as_float(r5.y));
                ACC2(q6, __int_as_float(r6.y));
                ACC2(q7, __int_as_float(r7.y));
            }
            const int e16 = s + ((e - s) & ~15);
            for (; j < e16; j += 16) {
                int2 r0 = stag[j + g];
                int2 r1 = stag[j + 4 + g];
                int2 r2 = stag[j + 8 + g];
                int2 r3 = stag[j + 12 + g];
                int2 q0 = *(const int2*)(hb + ((unsigned)r0.x + c4b));
                int2 q1 = *(const int2*)(hb + ((unsigned)r1.x + c4b));
                int2 q2 = *(const int2*)(hb + ((unsigned)r2.x + c4b));
                int2 q3 = *(const int2*)(hb + ((unsigned)r3.x + c4b));
                ACC2(q0, __int_as_float(r0.y));
                ACC2(q1, __int_as_float(r1.y));
                ACC2(q2, __int_as_float(r2.y));
                ACC2(q3, __int_as_float(r3.y));
            }
            for (; j < e; j += 8) {
                int j0 = j + g, j1 = j + 4 + g;
                int2 r0 = stag[j0 < e ? j0 : s];
                int2 r1 = stag[j1 < e ? j1 : s];
                float w0 = (j0 < e) ? __int_as_float(r0.y) : 0.f;
                float w1 = (j1 < e) ? __int_as_float(r1.y) : 0.f;
                int2 q0 = *(const int2*)(hb + ((unsigned)r0.x + c4b));
                int2 q1 = *(const int2*)(hb + ((unsigned)r1.x + c4b));
                ACC2(q0, w0);
                ACC2(q1, w1);
            }
            float acc[4] = {a01[0], a01[1], a23[0], a23[1]};
#pragma unroll
            for (int k = 0; k < 4; ++k) {
                float v = acc[k];
                v += __shfl_xor(v, 16, 64);
                v += __shfl_xor(v, 32, 64);
                acc[k] = v;
            }
            if (g == 0) {
                float di = dinv[n];
                float sc = di * di;  // self-loop: dinv[n]*1*dinv[n]*h[n]
                int2 qs = *(const int2*)(hb + (((size_t)(unsigned)n << 7) + c4b));
                float4 b = *(const float4*)(bconv + hh * 64 + c4);
                unsigned ux = (unsigned)qs.x, uy = (unsigned)qs.y;
                bf16x4 o;
                o[0] = (short)f2bf(fmaxf(di * acc[0] + sc * __uint_as_float(ux << 16) + b.x, 0.f));
                o[1] = (short)f2bf(fmaxf(di * acc[1] + sc * __uint_as_float(ux & 0xFFFF0000u) + b.y, 0.f));
                o[2] = (short)f2bf(fmaxf(di * acc[2] + sc * __uint_as_float(uy << 16) + b.z, 0.f));
                o[3] = (short)f2bf(fmaxf(di * acc[3] + sc * __uint_as_float(uy & 0xFFFF0000u) + b.w, 0.f));
                *(bf16x4*)(h2 + (size_t)n * 128 + hh * 64 + c4) = o;
            }
        }
    }
#undef ACC2
}

// ---- gemm23: out = relu(h2 @ Wf^T + bf) @ W2^T + b2, intermediate staged in LDS ----
__global__ __launch_bounds__(256) void gemm23_k(const unsigned short* __restrict__ h2,
                                                const unsigned short* __restrict__ Wfb,
                                                const float* __restrict__ bfc,
                                                const unsigned short* __restrict__ W2b,
                                                const float* __restrict__ b2,
                                                float* __restrict__ out, int M) {
    __shared__ __align__(16) unsigned short Wl[128 * 136];
    __shared__ __align__(16) unsigned short Tl[64 * 136];
    const int tid = threadIdx.x;

    // stage Wfb (bf16 dense) -> Wl (136-stride)
#pragma unroll
    for (int i = 0; i < 8; ++i) {
        int c = i * 256 + tid;
        int r = c >> 4, col = (c & 15) * 8;
        *(bf16x8*)&Wl[r * 136 + col] = *(const bf16x8*)(Wfb + c * 8);
    }
    __syncthreads();

    const int wave = tid >> 6, lane = tid & 63;
    const int m = lane & 15, quad = lane >> 4;
    const int rowBase = blockIdx.x * 64 + wave * 16;
    int arow = rowBase + m;
    int arowc = arow < M ? arow : (M - 1);

    bf16x8 afrag[4];
    {
        const unsigned short* pa = h2 + (size_t)arowc * 128 + quad * 8;
#pragma unroll
        for (int kc = 0; kc < 4; ++kc)
            afrag[kc] = *(const bf16x8*)(pa + kc * 32);
    }

    // stage 1: T = bf16(relu(h2 @ Wf^T + bf)) -> LDS
#pragma unroll
    for (int nt = 0; nt < 8; ++nt) {
        f32x4 acc = {0.f, 0.f, 0.f, 0.f};
        const unsigned short* wb = &Wl[(nt * 16 + m) * 136 + quad * 8];
#pragma unroll
        for (int kc = 0; kc < 4; ++kc) {
            bf16x8 bfrag = *(const bf16x8*)(wb + kc * 32);
            acc = __builtin_amdgcn_mfma_f32_16x16x32_bf16(afrag[kc], bfrag, acc, 0, 0, 0);
        }
        const int col = nt * 16 + m;
        float bv = bfc[col];
#pragma unroll
        for (int r = 0; r < 4; ++r) {
            int rowl = wave * 16 + quad * 4 + r;
            Tl[rowl * 136 + col] = f2bf(fmaxf(acc[r] + bv, 0.f));
        }
    }
    __syncthreads();

    // stage W2b (overwrite Wl)
#pragma unroll
    for (int i = 0; i < 8; ++i) {
        int c = i * 256 + tid;
        int r = c >> 4, col = (c & 15) * 8;
        *(bf16x8*)&Wl[r * 136 + col] = *(const bf16x8*)(W2b + c * 8);
    }
    __syncthreads();

    // stage 2: out = T @ W2^T + b2
    bf16x8 afrag2[4];
    {
        const unsigned short* pa = &Tl[(wave * 16 + m) * 136 + quad * 8];
#pragma unroll
        for (int kc = 0; kc < 4; ++kc)
            afrag2[kc] = *(const bf16x8*)(pa + kc * 32);
    }
#pragma unroll
    for (int nt = 0; nt < 8; ++nt) {
        f32x4 acc = {0.f, 0.f, 0.f, 0.f};
        const unsigned short* wb = &Wl[(nt * 16 + m) * 136 + quad * 8];
#pragma unroll
        for (int kc = 0; kc < 4; ++kc) {
            bf16x8 bfrag = *(const bf16x8*)(wb + kc * 32);
            acc = __builtin_amdgcn_mfma_f32_16x16x32_bf16(afrag2[kc], bfrag, acc, 0, 0, 0);
        }
        const int col = nt * 16 + m;
        float bv = b2[col];
#pragma unroll
        for (int r = 0; r < 4; ++r) {
            int row = rowBase + quad * 4 + r;
            if (row < M)
                out[(size_t)row * 128 + col] = acc[r] + bv;
        }
    }
}

extern "C" void kernel_launch(void* const* d_in, const int* in_sizes, int n_in,
                              void* d_out, int out_size, void* d_ws, size_t ws_size,
                              hipStream_t stream) {
    const float* x  = (const float*)d_in[0];
    const int* ei   = (const int*)d_in[1];
    const float* ew = (const float*)d_in[2];
    const float* Wc = (const float*)d_in[3];
    const float* bc = (const float*)d_in[4];
    const float* Wf = (const float*)d_in[5];
    const float* bf = (const float*)d_in[6];
    const float* W2 = (const float*)d_in[7];
    const float* b2 = (const float*)d_in[8];
    float* out = (float*)d_out;

    const int N = in_sizes[0] / 128;
    const int E = in_sizes[2];
    const int P = (N + PS - 1) / PS;  // 3125

    auto align256 = [](size_t v) { return (v + 255) & ~(size_t)255; };
    char* ws = (char*)d_ws;
    size_t off = 0;
    float* dinv  = (float*)(ws + off); off += align256((size_t)N * 4);
    int* partCnt = (int*)(ws + off);   off += align256((size_t)P * 4);
    unsigned short* wcb = (unsigned short*)(ws + off); off += align256(16384 * 2);
    unsigned short* wfb = (unsigned short*)(ws + off); off += align256(16384 * 2);
    unsigned short* w2b = (unsigned short*)(ws + off); off += align256(16384 * 2);
    unsigned short* h  = (unsigned short*)(ws + off); off += (size_t)N * 256;  // h'[2][N][64] channel-split
    unsigned short* h2 = (unsigned short*)(ws + off);

    // d_out scratch: partition regions P*CAPP*8B = 32.8MB <= 51.2MB,
    // consumed by aggF before gemm23 rewrites d_out.
    int2* regions = (int2*)out;

    const int EPB = (E + NB - 1) / NB;

    hipMemsetAsync(partCnt, 0, (size_t)P * 4, stream);
    scat_k<<<NB, 1024, 0, stream>>>(ei, ew, partCnt, regions, Wc, Wf, W2, wcb, wfb, w2b, E, P, EPB);
    deg_k<<<P, 256, 0, stream>>>(partCnt, regions, dinv, N);
    dgemm1_k<<<(N + 255) / 256, 256, 0, stream>>>(x, wcb, h, N);
    aggF_k<<<P, 256, 0, stream>>>(partCnt, regions, h, dinv, bc, h2, N);
    gemm23_k<<<(N + 63) / 64, 256, 0, stream>>>(h2, wfb, bf, w2b, b2, out, N);
}

// Round 6
// 372.966 us; speedup vs baseline: 1.2441x; 1.0282x over previous
//
#include <hip/hip_runtime.h>

typedef short bf16x8 __attribute__((ext_vector_type(8)));
typedef short bf16x4 __attribute__((ext_vector_type(4)));
typedef float f32x4 __attribute__((ext_vector_type(4)));
typedef float f32x2 __attribute__((ext_vector_type(2)));

#define PS 32        // nodes per partition
#define PMAX 4096    // max partitions supported (N <= 131072)
#define CAPP 1312    // region capacity: Poisson(1024) + 9 sigma
#define NB 256       // scat blocks (1024 threads each)

__device__ __forceinline__ unsigned short f2bf(float f) {
    unsigned int u = __float_as_uint(f);
    u = (u + 0x7FFFu + ((u >> 16) & 1u)) >> 16;
    return (unsigned short)u;
}

// ---- scat: fused histogram + scatter into fixed-capacity partition regions ----
// First 12 blocks pre-convert the three 128x128 weight matrices to bf16.
// (No per-edge global atomics: round-4 showed those cost 204MB of HBM writes.)
__global__ __launch_bounds__(1024) void scat_k(const int* __restrict__ ei,
                                               const float* __restrict__ ew,
                                               int* __restrict__ partCnt,
                                               int2* __restrict__ regions,
                                               const float* __restrict__ Wc,
                                               const float* __restrict__ Wf,
                                               const float* __restrict__ W2,
                                               unsigned short* __restrict__ wcb,
                                               unsigned short* __restrict__ wfb,
                                               unsigned short* __restrict__ w2b,
                                               int E, int P, int EPB) {
    __shared__ int cntl[PMAX];
    __shared__ int basel[PMAX];
    const int b = blockIdx.x, tid = threadIdx.x;

    if (b < 12) {  // weight prep: 12288 float4 chunks = 3 x 16384 elems
        int t = (b << 10) | tid;
        int a = t >> 12, idx = t & 4095;
        const float4* s4 = (const float4*)(a == 0 ? Wc : (a == 1 ? Wf : W2));
        unsigned short* dw = (a == 0 ? wcb : (a == 1 ? wfb : w2b));
        float4 v = s4[idx];
        ushort4 o;
        o.x = f2bf(v.x); o.y = f2bf(v.y); o.z = f2bf(v.z); o.w = f2bf(v.w);
        *(ushort4*)(dw + idx * 4) = o;
    }

    for (int i = tid; i < P; i += 1024) cntl[i] = 0;
    __syncthreads();
    const int s = b * EPB, e = min(E, s + EPB);
    for (int i = s + tid; i < e; i += 1024)
        atomicAdd(&cntl[ei[E + i] >> 5], 1);
    __syncthreads();
    for (int p = tid; p < P; p += 1024) {
        int c = cntl[p];
        basel[p] = p * CAPP + (c ? atomicAdd(&partCnt[p], c) : 0);
        cntl[p] = 0;
    }
    __syncthreads();
    for (int i = s + tid; i < e; i += 1024) {
        int src = ei[i];          // cold read
        int dst = ei[E + i];      // L2-hot (read in phase 1)
        float w = ew[i];
        int p = dst >> 5, dl = dst & 31;
        int lidx = atomicAdd(&cntl[p], 1);
        int pos = basel[p] + lidx;
        if (pos < (p + 1) * CAPP)  // overflow guard: statistically never
            regions[pos] = make_int2(src | (dl << 24), __float_as_int(w));
    }
}

// ---- deg_k: per-partition weighted in-degree + edge counts -> dinv, nodeOff ----
// One partition per block: coalesced read of ~1024 entries (26MB chip-wide),
// 32-counter LDS accumulate, width-32 scan for exclusive offsets.
__global__ __launch_bounds__(256) void deg_k(const int* __restrict__ partCnt,
                                             const int2* __restrict__ regions,
                                             float* __restrict__ dinv,
                                             int* __restrict__ nodeOff, int N) {
    __shared__ float degl[PS];
    __shared__ int cl[PS];
    const int p = blockIdx.x, tid = threadIdx.x;
    if (tid < PS) { degl[tid] = 0.f; cl[tid] = 0; }
    __syncthreads();
    const int cnt = min(partCnt[p], CAPP);
    const int2* reg = regions + (size_t)p * CAPP;
    for (int i = tid; i < cnt; i += 256) {
        int2 r = reg[i];
        int dl = (r.x >> 24) & 31;
        atomicAdd(&cl[dl], 1);
        atomicAdd(&degl[dl], __int_as_float(r.y));
    }
    __syncthreads();
    if (tid < PS) {  // lanes 0..31 of wave 0: exclusive scan of counts
        int cn = cl[tid];
        int v = cn;
#pragma unroll
        for (int off = 1; off < 32; off <<= 1) {
            int u = __shfl_up(v, off, 32);
            if (tid >= off) v += u;
        }
        int n = p * PS + tid;
        if (n < N) {
            nodeOff[n] = v - cn;
            dinv[n] = rsqrtf(1.0f + degl[tid]);  // self-loop weight 1
        }
    }
}

// ---- dgemm1: h' = bf16(dinv .* (x@Wc^T)), channel-split store ----
// dinv loaded coalesced (1KB/block); no regions read, no LDS atomics, no scan.
__global__ __launch_bounds__(256) void dgemm1_k(const float* __restrict__ x,
                                                const unsigned short* __restrict__ Wcb,
                                                const float* __restrict__ dinv,
                                                unsigned short* __restrict__ h,
                                                int M) {
    __shared__ __align__(16) unsigned short Wl[128 * 136];
    __shared__ float dloc[256];
    const int tid = threadIdx.x;

    {   // stage this block's 256 dinv values
        int node = blockIdx.x * 256 + tid;
        dloc[tid] = (node < M) ? dinv[node] : 0.f;
    }

    // stage Wcb (bf16 dense) -> Wl (136-stride); no conversion
#pragma unroll
    for (int i = 0; i < 8; ++i) {
        int c = i * 256 + tid;
        int r = c >> 4, col = (c & 15) * 8;
        *(bf16x8*)&Wl[r * 136 + col] = *(const bf16x8*)(Wcb + c * 8);
    }
    __syncthreads();

    const int wave = tid >> 6, lane = tid & 63;
    const int m = lane & 15, quad = lane >> 4;

#pragma unroll
    for (int t = 0; t < 4; ++t) {
        const int tileBase = blockIdx.x * 256 + t * 64;
        if (tileBase >= M) break;
        const int rowBase = tileBase + wave * 16;
        int arow = rowBase + m;
        int arowc = arow < M ? arow : (M - 1);

        bf16x8 afrag[4];
        const float* pa = x + (size_t)arowc * 128 + quad * 8;
#pragma unroll
        for (int kc = 0; kc < 4; ++kc) {
            float4 v0 = *(const float4*)(pa + kc * 32);
            float4 v1 = *(const float4*)(pa + kc * 32 + 4);
            bf16x8 f;
            f[0] = (short)f2bf(v0.x); f[1] = (short)f2bf(v0.y);
            f[2] = (short)f2bf(v0.z); f[3] = (short)f2bf(v0.w);
            f[4] = (short)f2bf(v1.x); f[5] = (short)f2bf(v1.y);
            f[6] = (short)f2bf(v1.z); f[7] = (short)f2bf(v1.w);
            afrag[kc] = f;
        }

        float dv[4];
#pragma unroll
        for (int r = 0; r < 4; ++r)
            dv[r] = dloc[t * 64 + wave * 16 + quad * 4 + r];

#pragma unroll
        for (int nt = 0; nt < 8; ++nt) {
            f32x4 acc = {0.f, 0.f, 0.f, 0.f};
            const unsigned short* wb = &Wl[(nt * 16 + m) * 136 + quad * 8];
#pragma unroll
            for (int kc = 0; kc < 4; ++kc) {
                bf16x8 bfrag = *(const bf16x8*)(wb + kc * 32);
                acc = __builtin_amdgcn_mfma_f32_16x16x32_bf16(afrag[kc], bfrag, acc, 0, 0, 0);
            }
            const int col = nt * 16 + m;
#pragma unroll
            for (int r = 0; r < 4; ++r) {
                int row = rowBase + quad * 4 + r;
                if (row < M)  // channel-split store: h[col>>6][row][col&63]
                    h[((size_t)(col >> 6) * M + row) * 64 + (col & 63)] = f2bf(acc[r] * dv[r]);
            }
        }
    }
}

// ---- aggF: LDS counting-sort (offsets precomputed by deg_k) + gather-reduce ----
// h2[n] = bf16(relu( dinv[n]*( sum w*h'[src] + h'[n] ) + b_conv ))
// Round-6: REVERTED round-5's chunk-key histogram sort + dinv fold (FETCH was
// unchanged at 325MB -> no locality gain; bank conflicts +56%, aggF +11us).
// This is the round-3 sort (proven 103.6us) with nodeOff now from deg_k.
__global__ __launch_bounds__(256) void aggF_k(const int* __restrict__ partCnt,
                                              const int* __restrict__ nodeOff,
                                              const int2* __restrict__ regions,
                                              const unsigned short* __restrict__ h,
                                              const float* __restrict__ dinv,
                                              const float* __restrict__ bconv,
                                              unsigned short* __restrict__ h2, int N) {
    __shared__ __align__(16) int2 stag[CAPP];
    __shared__ int cstart[PS + 1];
    __shared__ int wcur[PS];
    const int p = blockIdx.x, tid = threadIdx.x;
    const int cnt = min(partCnt[p], CAPP);
    const int2* reg = regions + (size_t)p * CAPP;

    if (tid < PS) {
        int node = p * PS + tid;
        int o = (node < N) ? nodeOff[node] : cnt;
        cstart[tid] = o;
        wcur[tid] = o;
    } else if (tid == PS) {
        cstart[PS] = cnt;
    }
    __syncthreads();
    // sort pass: pre-shift src index into the byte offset of its 128B half-line
    for (int i = tid; i < cnt; i += 256) {
        int2 r = reg[i];
        int pos = atomicAdd(&wcur[(r.x >> 24) & 31], 1);
        stag[pos] = make_int2((r.x & 0xFFFFFF) << 7, r.y);
    }
    __syncthreads();

    const int wave = tid >> 6, lane = tid & 63;
    const int g = lane >> 4;              // edge slot 0..3
    const int c4 = (lane & 15) * 4;       // channel base within the 64-ch half
    const int c4b = c4 * 2;               // ...as bytes

#define ACC2(q, w) {                                                        \
        unsigned ux = (unsigned)(q).x, uy = (unsigned)(q).y;                \
        f32x2 ww; ww[0] = (w); ww[1] = (w);                                 \
        f32x2 v01, v23;                                                     \
        v01[0] = __uint_as_float(ux << 16);                                 \
        v01[1] = __uint_as_float(ux & 0xFFFF0000u);                         \
        v23[0] = __uint_as_float(uy << 16);                                 \
        v23[1] = __uint_as_float(uy & 0xFFFF0000u);                         \
        a01 = v01 * ww + a01; a23 = v23 * ww + a23; }

#pragma unroll
    for (int hh = 0; hh < 2; ++hh) {
        const char* hb = (const char*)h + ((size_t)hh * (size_t)N << 7);
        for (int nl = wave; nl < PS; nl += 4) {
            int n = p * PS + nl;
            if (n >= N) continue;
            const int s = cstart[nl], e = cstart[nl + 1];
            f32x2 a01 = {0.f, 0.f}, a23 = {0.f, 0.f};
            int j = s;
            const int e32 = s + ((e - s) & ~31);
            for (; j < e32; j += 32) {
                int2 r0 = stag[j + g];
                int2 r1 = stag[j + 4 + g];
                int2 r2 = stag[j + 8 + g];
                int2 r3 = stag[j + 12 + g];
                int2 r4 = stag[j + 16 + g];
                int2 r5 = stag[j + 20 + g];
                int2 r6 = stag[j + 24 + g];
                int2 r7 = stag[j + 28 + g];
                int2 q0 = *(const int2*)(hb + ((unsigned)r0.x + c4b));
                int2 q1 = *(const int2*)(hb + ((unsigned)r1.x + c4b));
                int2 q2 = *(const int2*)(hb + ((unsigned)r2.x + c4b));
                int2 q3 = *(const int2*)(hb + ((unsigned)r3.x + c4b));
                int2 q4 = *(const int2*)(hb + ((unsigned)r4.x + c4b));
                int2 q5 = *(const int2*)(hb + ((unsigned)r5.x + c4b));
                int2 q6 = *(const int2*)(hb + ((unsigned)r6.x + c4b));
                int2 q7 = *(const int2*)(hb + ((unsigned)r7.x + c4b));
                ACC2(q0, __int_as_float(r0.y));
                ACC2(q1, __int_as_float(r1.y));
                ACC2(q2, __int_as_float(r2.y));
                ACC2(q3, __int_as_float(r3.y));
                ACC2(q4, __int_as_float(r4.y));
                ACC2(q5, __int_as_float(r5.y));
                ACC2(q6, __int_as_float(r6.y));
                ACC2(q7, __int_as_float(r7.y));
            }
            const int e16 = s + ((e - s) & ~15);
            for (; j < e16; j += 16) {
                int2 r0 = stag[j + g];
                int2 r1 = stag[j + 4 + g];
                int2 r2 = stag[j + 8 + g];
                int2 r3 = stag[j + 12 + g];
                int2 q0 = *(const int2*)(hb + ((unsigned)r0.x + c4b));
                int2 q1 = *(const int2*)(hb + ((unsigned)r1.x + c4b));
                int2 q2 = *(const int2*)(hb + ((unsigned)r2.x + c4b));
                int2 q3 = *(const int2*)(hb + ((unsigned)r3.x + c4b));
                ACC2(q0, __int_as_float(r0.y));
                ACC2(q1, __int_as_float(r1.y));
                ACC2(q2, __int_as_float(r2.y));
                ACC2(q3, __int_as_float(r3.y));
            }
            for (; j < e; j += 8) {
                int j0 = j + g, j1 = j + 4 + g;
                int2 r0 = stag[j0 < e ? j0 : s];
                int2 r1 = stag[j1 < e ? j1 : s];
                float w0 = (j0 < e) ? __int_as_float(r0.y) : 0.f;
                float w1 = (j1 < e) ? __int_as_float(r1.y) : 0.f;
                int2 q0 = *(const int2*)(hb + ((unsigned)r0.x + c4b));
                int2 q1 = *(const int2*)(hb + ((unsigned)r1.x + c4b));
                ACC2(q0, w0);
                ACC2(q1, w1);
            }
            float acc[4] = {a01[0], a01[1], a23[0], a23[1]};
#pragma unroll
            for (int k = 0; k < 4; ++k) {
                float v = acc[k];
                v += __shfl_xor(v, 16, 64);
                v += __shfl_xor(v, 32, 64);
                acc[k] = v;
            }
            if (g == 0) {
                float di = dinv[n];
                int2 qs = *(const int2*)(hb + (((size_t)(unsigned)n << 7) + c4b));
                float4 b = *(const float4*)(bconv + hh * 64 + c4);
                unsigned ux = (unsigned)qs.x, uy = (unsigned)qs.y;
                bf16x4 o;
                o[0] = (short)f2bf(fmaxf(di * (acc[0] + __uint_as_float(ux << 16)) + b.x, 0.f));
                o[1] = (short)f2bf(fmaxf(di * (acc[1] + __uint_as_float(ux & 0xFFFF0000u)) + b.y, 0.f));
                o[2] = (short)f2bf(fmaxf(di * (acc[2] + __uint_as_float(uy << 16)) + b.z, 0.f));
                o[3] = (short)f2bf(fmaxf(di * (acc[3] + __uint_as_float(uy & 0xFFFF0000u)) + b.w, 0.f));
                *(bf16x4*)(h2 + (size_t)n * 128 + hh * 64 + c4) = o;
            }
        }
    }
#undef ACC2
}

// ---- gemm23: out = relu(h2 @ Wf^T + bf) @ W2^T + b2, intermediate staged in LDS ----
__global__ __launch_bounds__(256) void gemm23_k(const unsigned short* __restrict__ h2,
                                                const unsigned short* __restrict__ Wfb,
                                                const float* __restrict__ bfc,
                                                const unsigned short* __restrict__ W2b,
                                                const float* __restrict__ b2,
                                                float* __restrict__ out, int M) {
    __shared__ __align__(16) unsigned short Wl[128 * 136];
    __shared__ __align__(16) unsigned short Tl[64 * 136];
    const int tid = threadIdx.x;

    // stage Wfb (bf16 dense) -> Wl (136-stride)
#pragma unroll
    for (int i = 0; i < 8; ++i) {
        int c = i * 256 + tid;
        int r = c >> 4, col = (c & 15) * 8;
        *(bf16x8*)&Wl[r * 136 + col] = *(const bf16x8*)(Wfb + c * 8);
    }
    __syncthreads();

    const int wave = tid >> 6, lane = tid & 63;
    const int m = lane & 15, quad = lane >> 4;
    const int rowBase = blockIdx.x * 64 + wave * 16;
    int arow = rowBase + m;
    int arowc = arow < M ? arow : (M - 1);

    bf16x8 afrag[4];
    {
        const unsigned short* pa = h2 + (size_t)arowc * 128 + quad * 8;
#pragma unroll
        for (int kc = 0; kc < 4; ++kc)
            afrag[kc] = *(const bf16x8*)(pa + kc * 32);
    }

    // stage 1: T = bf16(relu(h2 @ Wf^T + bf)) -> LDS
#pragma unroll
    for (int nt = 0; nt < 8; ++nt) {
        f32x4 acc = {0.f, 0.f, 0.f, 0.f};
        const unsigned short* wb = &Wl[(nt * 16 + m) * 136 + quad * 8];
#pragma unroll
        for (int kc = 0; kc < 4; ++kc) {
            bf16x8 bfrag = *(const bf16x8*)(wb + kc * 32);
            acc = __builtin_amdgcn_mfma_f32_16x16x32_bf16(afrag[kc], bfrag, acc, 0, 0, 0);
        }
        const int col = nt * 16 + m;
        float bv = bfc[col];
#pragma unroll
        for (int r = 0; r < 4; ++r) {
            int rowl = wave * 16 + quad * 4 + r;
            Tl[rowl * 136 + col] = f2bf(fmaxf(acc[r] + bv, 0.f));
        }
    }
    __syncthreads();

    // stage W2b (overwrite Wl)
#pragma unroll
    for (int i = 0; i < 8; ++i) {
        int c = i * 256 + tid;
        int r = c >> 4, col = (c & 15) * 8;
        *(bf16x8*)&Wl[r * 136 + col] = *(const bf16x8*)(W2b + c * 8);
    }
    __syncthreads();

    // stage 2: out = T @ W2^T + b2
    bf16x8 afrag2[4];
    {
        const unsigned short* pa = &Tl[(wave * 16 + m) * 136 + quad * 8];
#pragma unroll
        for (int kc = 0; kc < 4; ++kc)
            afrag2[kc] = *(const bf16x8*)(pa + kc * 32);
    }
#pragma unroll
    for (int nt = 0; nt < 8; ++nt) {
        f32x4 acc = {0.f, 0.f, 0.f, 0.f};
        const unsigned short* wb = &Wl[(nt * 16 + m) * 136 + quad * 8];
#pragma unroll
        for (int kc = 0; kc < 4; ++kc) {
            bf16x8 bfrag = *(const bf16x8*)(wb + kc * 32);
            acc = __builtin_amdgcn_mfma_f32_16x16x32_bf16(afrag2[kc], bfrag, acc, 0, 0, 0);
        }
        const int col = nt * 16 + m;
        float bv = b2[col];
#pragma unroll
        for (int r = 0; r < 4; ++r) {
            int row = rowBase + quad * 4 + r;
            if (row < M)
                out[(size_t)row * 128 + col] = acc[r] + bv;
        }
    }
}

extern "C" void kernel_launch(void* const* d_in, const int* in_sizes, int n_in,
                              void* d_out, int out_size, void* d_ws, size_t ws_size,
                              hipStream_t stream) {
    const float* x  = (const float*)d_in[0];
    const int* ei   = (const int*)d_in[1];
    const float* ew = (const float*)d_in[2];
    const float* Wc = (const float*)d_in[3];
    const float* bc = (const float*)d_in[4];
    const float* Wf = (const float*)d_in[5];
    const float* bf = (const float*)d_in[6];
    const float* W2 = (const float*)d_in[7];
    const float* b2 = (const float*)d_in[8];
    float* out = (float*)d_out;

    const int N = in_sizes[0] / 128;
    const int E = in_sizes[2];
    const int P = (N + PS - 1) / PS;  // 3125

    auto align256 = [](size_t v) { return (v + 255) & ~(size_t)255; };
    char* ws = (char*)d_ws;
    size_t off = 0;
    float* dinv  = (float*)(ws + off); off += align256((size_t)N * 4);
    int* nodeOff = (int*)(ws + off);   off += align256((size_t)N * 4);
    int* partCnt = (int*)(ws + off);   off += align256((size_t)P * 4);
    unsigned short* wcb = (unsigned short*)(ws + off); off += align256(16384 * 2);
    unsigned short* wfb = (unsigned short*)(ws + off); off += align256(16384 * 2);
    unsigned short* w2b = (unsigned short*)(ws + off); off += align256(16384 * 2);
    unsigned short* h  = (unsigned short*)(ws + off); off += (size_t)N * 256;  // h'[2][N][64] channel-split
    unsigned short* h2 = (unsigned short*)(ws + off);

    // d_out scratch: partition regions P*CAPP*8B = 32.8MB <= 51.2MB,
    // consumed by aggF before gemm23 rewrites d_out.
    int2* regions = (int2*)out;

    const int EPB = (E + NB - 1) / NB;

    hipMemsetAsync(partCnt, 0, (size_t)P * 4, stream);
    scat_k<<<NB, 1024, 0, stream>>>(ei, ew, partCnt, regions, Wc, Wf, W2, wcb, wfb, w2b, E, P, EPB);
    deg_k<<<P, 256, 0, stream>>>(partCnt, regions, dinv, nodeOff, N);
    dgemm1_k<<<(N + 255) / 256, 256, 0, stream>>>(x, wcb, dinv, h, N);
    aggF_k<<<P, 256, 0, stream>>>(partCnt, nodeOff, regions, h, dinv, bc, h2, N);
    gemm23_k<<<(N + 63) / 64, 256, 0, stream>>>(h2, wfb, bf, w2b, b2, out, N);
}

// Round 8
// 364.108 us; speedup vs baseline: 1.2743x; 1.0243x over previous
//
#include <hip/hip_runtime.h>

typedef short bf16x8 __attribute__((ext_vector_type(8)));
typedef short bf16x4 __attribute__((ext_vector_type(4)));
typedef float f32x4 __attribute__((ext_vector_type(4)));
typedef float f32x2 __attribute__((ext_vector_type(2)));

#define PS 32        // nodes per partition
#define PMAX 4096    // max partitions supported (N <= 131072)
#define CAPP 1312    // region capacity: Poisson(1024) + 9 sigma
#define NB 256       // scat blocks (1024 threads each)

__device__ __forceinline__ unsigned short f2bf(float f) {
    unsigned int u = __float_as_uint(f);
    u = (u + 0x7FFFu + ((u >> 16) & 1u)) >> 16;
    return (unsigned short)u;
}

// ---- scat: fused histogram + scatter into fixed-capacity partition regions ----
// First 12 blocks pre-convert the three 128x128 weight matrices to bf16.
// (No per-edge global atomics: round-4 showed those cost 204MB of HBM writes.)
__global__ __launch_bounds__(1024) void scat_k(const int* __restrict__ ei,
                                               const float* __restrict__ ew,
                                               int* __restrict__ partCnt,
                                               int2* __restrict__ regions,
                                               const float* __restrict__ Wc,
                                               const float* __restrict__ Wf,
                                               const float* __restrict__ W2,
                                               unsigned short* __restrict__ wcb,
                                               unsigned short* __restrict__ wfb,
                                               unsigned short* __restrict__ w2b,
                                               int E, int P, int EPB) {
    __shared__ int cntl[PMAX];
    __shared__ int basel[PMAX];
    const int b = blockIdx.x, tid = threadIdx.x;

    if (b < 12) {  // weight prep: 12288 float4 chunks = 3 x 16384 elems
        int t = (b << 10) | tid;
        int a = t >> 12, idx = t & 4095;
        const float4* s4 = (const float4*)(a == 0 ? Wc : (a == 1 ? Wf : W2));
        unsigned short* dw = (a == 0 ? wcb : (a == 1 ? wfb : w2b));
        float4 v = s4[idx];
        ushort4 o;
        o.x = f2bf(v.x); o.y = f2bf(v.y); o.z = f2bf(v.z); o.w = f2bf(v.w);
        *(ushort4*)(dw + idx * 4) = o;
    }

    for (int i = tid; i < P; i += 1024) cntl[i] = 0;
    __syncthreads();
    const int s = b * EPB, e = min(E, s + EPB);
    for (int i = s + tid; i < e; i += 1024)
        atomicAdd(&cntl[ei[E + i] >> 5], 1);
    __syncthreads();
    for (int p = tid; p < P; p += 1024) {
        int c = cntl[p];
        basel[p] = p * CAPP + (c ? atomicAdd(&partCnt[p], c) : 0);
        cntl[p] = 0;
    }
    __syncthreads();
    for (int i = s + tid; i < e; i += 1024) {
        int src = ei[i];          // cold read
        int dst = ei[E + i];      // L2-hot (read in phase 1)
        float w = ew[i];
        int p = dst >> 5, dl = dst & 31;
        int lidx = atomicAdd(&cntl[p], 1);
        int pos = basel[p] + lidx;
        if (pos < (p + 1) * CAPP)  // overflow guard: statistically never
            regions[pos] = make_int2(src | (dl << 24), __float_as_int(w));
    }
}

// ---- dgemm1: fused {degree+scan -> dinv,nodeOff} + h' = bf16(dinv .* x@Wc^T) ----
// Round-7: deg_k deleted; 64-row blocks (1563, ~4/CU vs old 391 @1.5/CU).
// Each block owns 2 partitions: reads their ~16KB of region entries (same
// bytes deg_k read, now overlapped with W-staging and other blocks' MFMA),
// 64-counter LDS accumulate, width-32 scan, then the GEMM tile.
__global__ __launch_bounds__(256) void dgemm1_k(const float* __restrict__ x,
                                                const unsigned short* __restrict__ Wcb,
                                                const int* __restrict__ partCnt,
                                                const int2* __restrict__ regions,
                                                float* __restrict__ dinv,
                                                int* __restrict__ nodeOff,
                                                unsigned short* __restrict__ h,
                                                int M, int P) {
    __shared__ __align__(16) unsigned short Wl[128 * 136];
    __shared__ float degl[64];
    __shared__ int cl[64];
    __shared__ float dl64[64];
    const int tid = threadIdx.x;
    if (tid < 64) { degl[tid] = 0.f; cl[tid] = 0; }

    // stage Wcb (bf16 dense) -> Wl (136-stride); no conversion
#pragma unroll
    for (int i = 0; i < 8; ++i) {
        int c = i * 256 + tid;
        int r = c >> 4, col = (c & 15) * 8;
        *(bf16x8*)&Wl[r * 136 + col] = *(const bf16x8*)(Wcb + c * 8);
    }
    __syncthreads();

    // degree + count accumulation for partitions 2b, 2b+1
#pragma unroll
    for (int q = 0; q < 2; ++q) {
        int p = blockIdx.x * 2 + q;
        if (p < P) {
            const int cnt = min(partCnt[p], CAPP);
            const int2* reg = regions + (size_t)p * CAPP;
            for (int i = tid; i < cnt; i += 256) {
                int2 r = reg[i];
                int dl = q * 32 + ((r.x >> 24) & 31);
                atomicAdd(&cl[dl], 1);
                atomicAdd(&degl[dl], __int_as_float(r.y));
            }
        }
    }
    __syncthreads();
    if (tid < 64) {  // lanes 0..63 of wave 0: two width-32 segmented scans
        int cn = cl[tid];
        int v = cn;
#pragma unroll
        for (int off = 1; off < 32; off <<= 1) {
            int u = __shfl_up(v, off, 32);
            if ((tid & 31) >= off) v += u;
        }
        int node = blockIdx.x * 64 + tid;
        float d = rsqrtf(1.0f + degl[tid]);  // self-loop weight 1
        if (node < M) { nodeOff[node] = v - cn; dinv[node] = d; }
        dl64[tid] = d;
    }
    __syncthreads();

    const int wave = tid >> 6, lane = tid & 63;
    const int m = lane & 15, quad = lane >> 4;
    const int rowBase = blockIdx.x * 64 + wave * 16;
    int arow = rowBase + m;
    int arowc = arow < M ? arow : (M - 1);

    bf16x8 afrag[4];
    const float* pa = x + (size_t)arowc * 128 + quad * 8;
#pragma unroll
    for (int kc = 0; kc < 4; ++kc) {
        float4 v0 = *(const float4*)(pa + kc * 32);
        float4 v1 = *(const float4*)(pa + kc * 32 + 4);
        bf16x8 f;
        f[0] = (short)f2bf(v0.x); f[1] = (short)f2bf(v0.y);
        f[2] = (short)f2bf(v0.z); f[3] = (short)f2bf(v0.w);
        f[4] = (short)f2bf(v1.x); f[5] = (short)f2bf(v1.y);
        f[6] = (short)f2bf(v1.z); f[7] = (short)f2bf(v1.w);
        afrag[kc] = f;
    }

    float dv[4];
#pragma unroll
    for (int r = 0; r < 4; ++r)
        dv[r] = dl64[wave * 16 + quad * 4 + r];

#pragma unroll
    for (int nt = 0; nt < 8; ++nt) {
        f32x4 acc = {0.f, 0.f, 0.f, 0.f};
        const unsigned short* wb = &Wl[(nt * 16 + m) * 136 + quad * 8];
#pragma unroll
        for (int kc = 0; kc < 4; ++kc) {
            bf16x8 bfrag = *(const bf16x8*)(wb + kc * 32);
            acc = __builtin_amdgcn_mfma_f32_16x16x32_bf16(afrag[kc], bfrag, acc, 0, 0, 0);
        }
        const int col = nt * 16 + m;
#pragma unroll
        for (int r = 0; r < 4; ++r) {
            int row = rowBase + quad * 4 + r;
            if (row < M)  // channel-split store: h[col>>6][row][col&63]
                h[((size_t)(col >> 6) * M + row) * 64 + (col & 63)] = f2bf(acc[r] * dv[r]);
        }
    }
}

// ---- aggF: LDS counting-sort (offsets from dgemm1) + gather-reduce ----
// h2[n] = bf16(relu( dinv[n]*( sum w*h'[src] + h'[n] ) + b_conv ))
// Proven round-3/round-6 form: 103.5us, FETCH 325MB, conflicts 674K.
__global__ __launch_bounds__(256) void aggF_k(const int* __restrict__ partCnt,
                                              const int* __restrict__ nodeOff,
                                              const int2* __restrict__ regions,
                                              const unsigned short* __restrict__ h,
                                              const float* __restrict__ dinv,
                                              const float* __restrict__ bconv,
                                              unsigned short* __restrict__ h2, int N) {
    __shared__ __align__(16) int2 stag[CAPP];
    __shared__ int cstart[PS + 1];
    __shared__ int wcur[PS];
    const int p = blockIdx.x, tid = threadIdx.x;
    const int cnt = min(partCnt[p], CAPP);
    const int2* reg = regions + (size_t)p * CAPP;

    if (tid < PS) {
        int node = p * PS + tid;
        int o = (node < N) ? nodeOff[node] : cnt;
        cstart[tid] = o;
        wcur[tid] = o;
    } else if (tid == PS) {
        cstart[PS] = cnt;
    }
    __syncthreads();
    // sort pass: pre-shift src index into the byte offset of its 128B half-line
    for (int i = tid; i < cnt; i += 256) {
        int2 r = reg[i];
        int pos = atomicAdd(&wcur[(r.x >> 24) & 31], 1);
        stag[pos] = make_int2((r.x & 0xFFFFFF) << 7, r.y);
    }
    __syncthreads();

    const int wave = tid >> 6, lane = tid & 63;
    const int g = lane >> 4;              // edge slot 0..3
    const int c4 = (lane & 15) * 4;       // channel base within the 64-ch half
    const int c4b = c4 * 2;               // ...as bytes

#define ACC2(q, w) {                                                        \
        unsigned ux = (unsigned)(q).x, uy = (unsigned)(q).y;                \
        f32x2 ww; ww[0] = (w); ww[1] = (w);                                 \
        f32x2 v01, v23;                                                     \
        v01[0] = __uint_as_float(ux << 16);                                 \
        v01[1] = __uint_as_float(ux & 0xFFFF0000u);                         \
        v23[0] = __uint_as_float(uy << 16);                                 \
        v23[1] = __uint_as_float(uy & 0xFFFF0000u);                         \
        a01 = v01 * ww + a01; a23 = v23 * ww + a23; }

#pragma unroll
    for (int hh = 0; hh < 2; ++hh) {
        const char* hb = (const char*)h + ((size_t)hh * (size_t)N << 7);
        for (int nl = wave; nl < PS; nl += 4) {
            int n = p * PS + nl;
            if (n >= N) continue;
            const int s = cstart[nl], e = cstart[nl + 1];
            f32x2 a01 = {0.f, 0.f}, a23 = {0.f, 0.f};
            int j = s;
            const int e32 = s + ((e - s) & ~31);
            for (; j < e32; j += 32) {
                int2 r0 = stag[j + g];
                int2 r1 = stag[j + 4 + g];
                int2 r2 = stag[j + 8 + g];
                int2 r3 = stag[j + 12 + g];
                int2 r4 = stag[j + 16 + g];
                int2 r5 = stag[j + 20 + g];
                int2 r6 = stag[j + 24 + g];
                int2 r7 = stag[j + 28 + g];
                int2 q0 = *(const int2*)(hb + ((unsigned)r0.x + c4b));
                int2 q1 = *(const int2*)(hb + ((unsigned)r1.x + c4b));
                int2 q2 = *(const int2*)(hb + ((unsigned)r2.x + c4b));
                int2 q3 = *(const int2*)(hb + ((unsigned)r3.x + c4b));
                int2 q4 = *(const int2*)(hb + ((unsigned)r4.x + c4b));
                int2 q5 = *(const int2*)(hb + ((unsigned)r5.x + c4b));
                int2 q6 = *(const int2*)(hb + ((unsigned)r6.x + c4b));
                int2 q7 = *(const int2*)(hb + ((unsigned)r7.x + c4b));
                ACC2(q0, __int_as_float(r0.y));
                ACC2(q1, __int_as_float(r1.y));
                ACC2(q2, __int_as_float(r2.y));
                ACC2(q3, __int_as_float(r3.y));
                ACC2(q4, __int_as_float(r4.y));
                ACC2(q5, __int_as_float(r5.y));
                ACC2(q6, __int_as_float(r6.y));
                ACC2(q7, __int_as_float(r7.y));
            }
            const int e16 = s + ((e - s) & ~15);
            for (; j < e16; j += 16) {
                int2 r0 = stag[j + g];
                int2 r1 = stag[j + 4 + g];
                int2 r2 = stag[j + 8 + g];
                int2 r3 = stag[j + 12 + g];
                int2 q0 = *(const int2*)(hb + ((unsigned)r0.x + c4b));
                int2 q1 = *(const int2*)(hb + ((unsigned)r1.x + c4b));
                int2 q2 = *(const int2*)(hb + ((unsigned)r2.x + c4b));
                int2 q3 = *(const int2*)(hb + ((unsigned)r3.x + c4b));
                ACC2(q0, __int_as_float(r0.y));
                ACC2(q1, __int_as_float(r1.y));
                ACC2(q2, __int_as_float(r2.y));
                ACC2(q3, __int_as_float(r3.y));
            }
            for (; j < e; j += 8) {
                int j0 = j + g, j1 = j + 4 + g;
                int2 r0 = stag[j0 < e ? j0 : s];
                int2 r1 = stag[j1 < e ? j1 : s];
                float w0 = (j0 < e) ? __int_as_float(r0.y) : 0.f;
                float w1 = (j1 < e) ? __int_as_float(r1.y) : 0.f;
                int2 q0 = *(const int2*)(hb + ((unsigned)r0.x + c4b));
                int2 q1 = *(const int2*)(hb + ((unsigned)r1.x + c4b));
                ACC2(q0, w0);
                ACC2(q1, w1);
            }
            float acc[4] = {a01[0], a01[1], a23[0], a23[1]};
#pragma unroll
            for (int k = 0; k < 4; ++k) {
                float v = acc[k];
                v += __shfl_xor(v, 16, 64);
                v += __shfl_xor(v, 32, 64);
                acc[k] = v;
            }
            if (g == 0) {
                float di = dinv[n];
                int2 qs = *(const int2*)(hb + (((size_t)(unsigned)n << 7) + c4b));
                float4 b = *(const float4*)(bconv + hh * 64 + c4);
                unsigned ux = (unsigned)qs.x, uy = (unsigned)qs.y;
                bf16x4 o;
                o[0] = (short)f2bf(fmaxf(di * (acc[0] + __uint_as_float(ux << 16)) + b.x, 0.f));
                o[1] = (short)f2bf(fmaxf(di * (acc[1] + __uint_as_float(ux & 0xFFFF0000u)) + b.y, 0.f));
                o[2] = (short)f2bf(fmaxf(di * (acc[2] + __uint_as_float(uy << 16)) + b.z, 0.f));
                o[3] = (short)f2bf(fmaxf(di * (acc[3] + __uint_as_float(uy & 0xFFFF0000u)) + b.w, 0.f));
                *(bf16x4*)(h2 + (size_t)n * 128 + hh * 64 + c4) = o;
            }
        }
    }
#undef ACC2
}

// ---- gemm23: out = relu(h2 @ Wf^T + bf) @ W2^T + b2, intermediate staged in LDS ----
__global__ __launch_bounds__(256) void gemm23_k(const unsigned short* __restrict__ h2,
                                                const unsigned short* __restrict__ Wfb,
                                                const float* __restrict__ bfc,
                                                const unsigned short* __restrict__ W2b,
                                                const float* __restrict__ b2,
                                                float* __restrict__ out, int M) {
    __shared__ __align__(16) unsigned short Wl[128 * 136];
    __shared__ __align__(16) unsigned short Tl[64 * 136];
    const int tid = threadIdx.x;

    // stage Wfb (bf16 dense) -> Wl (136-stride)
#pragma unroll
    for (int i = 0; i < 8; ++i) {
        int c = i * 256 + tid;
        int r = c >> 4, col = (c & 15) * 8;
        *(bf16x8*)&Wl[r * 136 + col] = *(const bf16x8*)(Wfb + c * 8);
    }
    __syncthreads();

    const int wave = tid >> 6, lane = tid & 63;
    const int m = lane & 15, quad = lane >> 4;
    const int rowBase = blockIdx.x * 64 + wave * 16;
    int arow = rowBase + m;
    int arowc = arow < M ? arow : (M - 1);

    bf16x8 afrag[4];
    {
        const unsigned short* pa = h2 + (size_t)arowc * 128 + quad * 8;
#pragma unroll
        for (int kc = 0; kc < 4; ++kc)
            afrag[kc] = *(const bf16x8*)(pa + kc * 32);
    }

    // stage 1: T = bf16(relu(h2 @ Wf^T + bf)) -> LDS
#pragma unroll
    for (int nt = 0; nt < 8; ++nt) {
        f32x4 acc = {0.f, 0.f, 0.f, 0.f};
        const unsigned short* wb = &Wl[(nt * 16 + m) * 136 + quad * 8];
#pragma unroll
        for (int kc = 0; kc < 4; ++kc) {
            bf16x8 bfrag = *(const bf16x8*)(wb + kc * 32);
            acc = __builtin_amdgcn_mfma_f32_16x16x32_bf16(afrag[kc], bfrag, acc, 0, 0, 0);
        }
        const int col = nt * 16 + m;
        float bv = bfc[col];
#pragma unroll
        for (int r = 0; r < 4; ++r) {
            int rowl = wave * 16 + quad * 4 + r;
            Tl[rowl * 136 + col] = f2bf(fmaxf(acc[r] + bv, 0.f));
        }
    }
    __syncthreads();

    // stage W2b (overwrite Wl)
#pragma unroll
    for (int i = 0; i < 8; ++i) {
        int c = i * 256 + tid;
        int r = c >> 4, col = (c & 15) * 8;
        *(bf16x8*)&Wl[r * 136 + col] = *(const bf16x8*)(W2b + c * 8);
    }
    __syncthreads();

    // stage 2: out = T @ W2^T + b2
    bf16x8 afrag2[4];
    {
        const unsigned short* pa = &Tl[(wave * 16 + m) * 136 + quad * 8];
#pragma unroll
        for (int kc = 0; kc < 4; ++kc)
            afrag2[kc] = *(const bf16x8*)(pa + kc * 32);
    }
#pragma unroll
    for (int nt = 0; nt < 8; ++nt) {
        f32x4 acc = {0.f, 0.f, 0.f, 0.f};
        const unsigned short* wb = &Wl[(nt * 16 + m) * 136 + quad * 8];
#pragma unroll
        for (int kc = 0; kc < 4; ++kc) {
            bf16x8 bfrag = *(const bf16x8*)(wb + kc * 32);
            acc = __builtin_amdgcn_mfma_f32_16x16x32_bf16(afrag2[kc], bfrag, acc, 0, 0, 0);
        }
        const int col = nt * 16 + m;
        float bv = b2[col];
#pragma unroll
        for (int r = 0; r < 4; ++r) {
            int row = rowBase + quad * 4 + r;
            if (row < M)
                out[(size_t)row * 128 + col] = acc[r] + bv;
        }
    }
}

extern "C" void kernel_launch(void* const* d_in, const int* in_sizes, int n_in,
                              void* d_out, int out_size, void* d_ws, size_t ws_size,
                              hipStream_t stream) {
    const float* x  = (const float*)d_in[0];
    const int* ei   = (const int*)d_in[1];
    const float* ew = (const float*)d_in[2];
    const float* Wc = (const float*)d_in[3];
    const float* bc = (const float*)d_in[4];
    const float* Wf = (const float*)d_in[5];
    const float* bf = (const float*)d_in[6];
    const float* W2 = (const float*)d_in[7];
    const float* b2 = (const float*)d_in[8];
    float* out = (float*)d_out;

    const int N = in_sizes[0] / 128;
    const int E = in_sizes[2];
    const int P = (N + PS - 1) / PS;  // 3125

    auto align256 = [](size_t v) { return (v + 255) & ~(size_t)255; };
    char* ws = (char*)d_ws;
    size_t off = 0;
    float* dinv  = (float*)(ws + off); off += align256((size_t)N * 4);
    int* nodeOff = (int*)(ws + off);   off += align256((size_t)N * 4);
    int* partCnt = (int*)(ws + off);   off += align256((size_t)P * 4);
    unsigned short* wcb = (unsigned short*)(ws + off); off += align256(16384 * 2);
    unsigned short* wfb = (unsigned short*)(ws + off); off += align256(16384 * 2);
    unsigned short* w2b = (unsigned short*)(ws + off); off += align256(16384 * 2);
    unsigned short* h  = (unsigned short*)(ws + off); off += (size_t)N * 256;  // h'[2][N][64] channel-split
    unsigned short* h2 = (unsigned short*)(ws + off);

    // d_out scratch: partition regions P*CAPP*8B = 32.8MB <= 51.2MB,
    // consumed by aggF before gemm23 rewrites d_out.
    int2* regions = (int2*)out;

    const int EPB = (E + NB - 1) / NB;

    hipMemsetAsync(partCnt, 0, (size_t)P * 4, stream);
    scat_k<<<NB, 1024, 0, stream>>>(ei, ew, partCnt, regions, Wc, Wf, W2, wcb, wfb, w2b, E, P, EPB);
    dgemm1_k<<<(N + 63) / 64, 256, 0, stream>>>(x, wcb, partCnt, regions, dinv, nodeOff, h, N, P);
    aggF_k<<<P, 256, 0, stream>>>(partCnt, nodeOff, regions, h, dinv, bc, h2, N);
    gemm23_k<<<(N + 63) / 64, 256, 0, stream>>>(h2, wfb, bf, w2b, b2, out, N);
}

// Round 9
// 337.504 us; speedup vs baseline: 1.3748x; 1.0788x over previous
//
#include <hip/hip_runtime.h>

typedef short bf16x8 __attribute__((ext_vector_type(8)));
typedef short bf16x4 __attribute__((ext_vector_type(4)));
typedef float f32x4 __attribute__((ext_vector_type(4)));
typedef float f32x2 __attribute__((ext_vector_type(2)));

#define PS 32        // nodes per partition
#define CAPP 1312    // region capacity: Poisson(1024) + 9 sigma
#define NB 256       // scatA blocks (1024 threads each)
#define CAPB 17536   // bucket staging capacity: Poisson(16327) + ~9.5 sigma
// bucket = 512 nodes = 16 partitions (dst>>9); NBK = ceil(N/512) <= 256

__device__ __forceinline__ unsigned short f2bf(float f) {
    unsigned int u = __float_as_uint(f);
    u = (u + 0x7FFFu + ((u >> 16) & 1u)) >> 16;
    return (unsigned short)u;
}

// ---- scatA: histogram by bucket + COALESCED bucket-run scatter + weight prep ----
// Round-9: replaces the direct 3125-partition scatter (3.2M x 8B random stores
// ~= 200MB write-amplified HBM traffic, round-4 counters). Each block writes
// ~64-edge (512B) contiguous runs per bucket -> full-line writes, 25.6MB exact.
// Staging entry packs src(17b) | dl(5b)<<17 | p_local(4b)<<22 (N<=131072).
__global__ __launch_bounds__(1024) void scatA_k(const int* __restrict__ ei,
                                                const float* __restrict__ ew,
                                                int* __restrict__ bucketCnt,
                                                int2* __restrict__ bstage,
                                                const float* __restrict__ Wc,
                                                const float* __restrict__ Wf,
                                                const float* __restrict__ W2,
                                                unsigned short* __restrict__ wcb,
                                                unsigned short* __restrict__ wfb,
                                                unsigned short* __restrict__ w2b,
                                                int E, int NBK, int EPB) {
    __shared__ int cntl[256];
    __shared__ int basel[256];
    const int b = blockIdx.x, tid = threadIdx.x;

    if (b < 12) {  // weight prep: 12288 float4 chunks = 3 x 16384 elems
        int t = (b << 10) | tid;
        int a = t >> 12, idx = t & 4095;
        const float4* s4 = (const float4*)(a == 0 ? Wc : (a == 1 ? Wf : W2));
        unsigned short* dw = (a == 0 ? wcb : (a == 1 ? wfb : w2b));
        float4 v = s4[idx];
        ushort4 o;
        o.x = f2bf(v.x); o.y = f2bf(v.y); o.z = f2bf(v.z); o.w = f2bf(v.w);
        *(ushort4*)(dw + idx * 4) = o;
    }

    if (tid < 256) cntl[tid] = 0;
    __syncthreads();
    const int s = b * EPB, e = min(E, s + EPB);
    for (int i = s + tid; i < e; i += 1024)
        atomicAdd(&cntl[ei[E + i] >> 9], 1);
    __syncthreads();
    if (tid < NBK) {
        int c = cntl[tid];
        basel[tid] = tid * CAPB + (c ? atomicAdd(&bucketCnt[tid], c) : 0);
        cntl[tid] = 0;
    }
    __syncthreads();
    for (int i = s + tid; i < e; i += 1024) {
        int src = ei[i];          // cold read
        int dst = ei[E + i];      // L2-hot (read in phase 1)
        float w = ew[i];
        int bk = dst >> 9;
        int lidx = atomicAdd(&cntl[bk], 1);
        int pos = basel[bk] + lidx;
        if (pos < (bk + 1) * CAPB)  // overflow guard: statistically never
            bstage[pos] = make_int2(src | ((dst & 31) << 17) | (((dst >> 5) & 15) << 22),
                                    __float_as_int(w));
    }
}

// ---- scatB: per-bucket scatter into partition-major regions + partCnt ----
// One bucket per block: the 16 partitions' region windows total 168KB ->
// fully L2-resident; lines get fully dirtied before eviction -> write-back
// ~= useful bytes. partCnt written directly (exclusive ownership, no memset).
__global__ __launch_bounds__(1024) void scatB_k(const int* __restrict__ bucketCnt,
                                                const int2* __restrict__ bstage,
                                                int* __restrict__ partCnt,
                                                int2* __restrict__ regions,
                                                int P) {
    __shared__ int cl[16];
    __shared__ int cur[16];
    const int bk = blockIdx.x, tid = threadIdx.x;
    const int cnt = min(bucketCnt[bk], CAPB);
    const int2* bs = bstage + (size_t)bk * CAPB;

    if (tid < 16) cl[tid] = 0;
    __syncthreads();
    for (int i = tid; i < cnt; i += 1024)
        atomicAdd(&cl[((unsigned)bs[i].x >> 22) & 15], 1);
    __syncthreads();
    if (tid < 16) {
        int p = bk * 16 + tid;
        if (p < P) partCnt[p] = cl[tid];
        cur[tid] = 0;
    }
    __syncthreads();
    for (int i = tid; i < cnt; i += 1024) {
        int2 r = bs[i];
        unsigned x = (unsigned)r.x;
        int pl = (x >> 22) & 15;
        int pos = atomicAdd(&cur[pl], 1);
        if (pos < CAPP) {
            int p = bk * 16 + pl;
            // rebuild downstream entry format: src | dl<<24
            regions[(size_t)p * CAPP + pos] =
                make_int2((int)(x & 0x1FFFFu) | (int)(((x >> 17) & 31u) << 24), r.y);
        }
    }
}

// ---- dgemm1: fused {degree+scan -> dinv,nodeOff} + h' = bf16(dinv .* x@Wc^T) ----
// 64-row blocks (1563, ~4/CU). Each block owns 2 partitions: reads their
// ~16KB of region entries, 64-counter LDS accumulate, width-32 scan, GEMM tile.
__global__ __launch_bounds__(256) void dgemm1_k(const float* __restrict__ x,
                                                const unsigned short* __restrict__ Wcb,
                                                const int* __restrict__ partCnt,
                                                const int2* __restrict__ regions,
                                                float* __restrict__ dinv,
                                                int* __restrict__ nodeOff,
                                                unsigned short* __restrict__ h,
                                                int M, int P) {
    __shared__ __align__(16) unsigned short Wl[128 * 136];
    __shared__ float degl[64];
    __shared__ int cl[64];
    __shared__ float dl64[64];
    const int tid = threadIdx.x;
    if (tid < 64) { degl[tid] = 0.f; cl[tid] = 0; }

    // stage Wcb (bf16 dense) -> Wl (136-stride); no conversion
#pragma unroll
    for (int i = 0; i < 8; ++i) {
        int c = i * 256 + tid;
        int r = c >> 4, col = (c & 15) * 8;
        *(bf16x8*)&Wl[r * 136 + col] = *(const bf16x8*)(Wcb + c * 8);
    }
    __syncthreads();

    // degree + count accumulation for partitions 2b, 2b+1
#pragma unroll
    for (int q = 0; q < 2; ++q) {
        int p = blockIdx.x * 2 + q;
        if (p < P) {
            const int cnt = min(partCnt[p], CAPP);
            const int2* reg = regions + (size_t)p * CAPP;
            for (int i = tid; i < cnt; i += 256) {
                int2 r = reg[i];
                int dl = q * 32 + ((r.x >> 24) & 31);
                atomicAdd(&cl[dl], 1);
                atomicAdd(&degl[dl], __int_as_float(r.y));
            }
        }
    }
    __syncthreads();
    if (tid < 64) {  // lanes 0..63 of wave 0: two width-32 segmented scans
        int cn = cl[tid];
        int v = cn;
#pragma unroll
        for (int off = 1; off < 32; off <<= 1) {
            int u = __shfl_up(v, off, 32);
            if ((tid & 31) >= off) v += u;
        }
        int node = blockIdx.x * 64 + tid;
        float d = rsqrtf(1.0f + degl[tid]);  // self-loop weight 1
        if (node < M) { nodeOff[node] = v - cn; dinv[node] = d; }
        dl64[tid] = d;
    }
    __syncthreads();

    const int wave = tid >> 6, lane = tid & 63;
    const int m = lane & 15, quad = lane >> 4;
    const int rowBase = blockIdx.x * 64 + wave * 16;
    int arow = rowBase + m;
    int arowc = arow < M ? arow : (M - 1);

    bf16x8 afrag[4];
    const float* pa = x + (size_t)arowc * 128 + quad * 8;
#pragma unroll
    for (int kc = 0; kc < 4; ++kc) {
        float4 v0 = *(const float4*)(pa + kc * 32);
        float4 v1 = *(const float4*)(pa + kc * 32 + 4);
        bf16x8 f;
        f[0] = (short)f2bf(v0.x); f[1] = (short)f2bf(v0.y);
        f[2] = (short)f2bf(v0.z); f[3] = (short)f2bf(v0.w);
        f[4] = (short)f2bf(v1.x); f[5] = (short)f2bf(v1.y);
        f[6] = (short)f2bf(v1.z); f[7] = (short)f2bf(v1.w);
        afrag[kc] = f;
    }

    float dv[4];
#pragma unroll
    for (int r = 0; r < 4; ++r)
        dv[r] = dl64[wave * 16 + quad * 4 + r];

#pragma unroll
    for (int nt = 0; nt < 8; ++nt) {
        f32x4 acc = {0.f, 0.f, 0.f, 0.f};
        const unsigned short* wb = &Wl[(nt * 16 + m) * 136 + quad * 8];
#pragma unroll
        for (int kc = 0; kc < 4; ++kc) {
            bf16x8 bfrag = *(const bf16x8*)(wb + kc * 32);
            acc = __builtin_amdgcn_mfma_f32_16x16x32_bf16(afrag[kc], bfrag, acc, 0, 0, 0);
        }
        const int col = nt * 16 + m;
#pragma unroll
        for (int r = 0; r < 4; ++r) {
            int row = rowBase + quad * 4 + r;
            if (row < M)  // channel-split store: h[col>>6][row][col&63]
                h[((size_t)(col >> 6) * M + row) * 64 + (col & 63)] = f2bf(acc[r] * dv[r]);
        }
    }
}

// ---- aggF: LDS counting-sort (offsets from dgemm1) + gather-reduce ----
// h2[n] = bf16(relu( dinv[n]*( sum w*h'[src] + h'[n] ) + b_conv ))
// Proven form: ~104us, FETCH 325MB, conflicts 674K (local roofline for this
// random-128B-gather pattern; rounds 1-6 pinned all structural variants here).
__global__ __launch_bounds__(256) void aggF_k(const int* __restrict__ partCnt,
                                              const int* __restrict__ nodeOff,
                                              const int2* __restrict__ regions,
                                              const unsigned short* __restrict__ h,
                                              const float* __restrict__ dinv,
                                              const float* __restrict__ bconv,
                                              unsigned short* __restrict__ h2, int N) {
    __shared__ __align__(16) int2 stag[CAPP];
    __shared__ int cstart[PS + 1];
    __shared__ int wcur[PS];
    const int p = blockIdx.x, tid = threadIdx.x;
    const int cnt = min(partCnt[p], CAPP);
    const int2* reg = regions + (size_t)p * CAPP;

    if (tid < PS) {
        int node = p * PS + tid;
        int o = (node < N) ? nodeOff[node] : cnt;
        cstart[tid] = o;
        wcur[tid] = o;
    } else if (tid == PS) {
        cstart[PS] = cnt;
    }
    __syncthreads();
    // sort pass: pre-shift src index into the byte offset of its 128B half-line
    for (int i = tid; i < cnt; i += 256) {
        int2 r = reg[i];
        int pos = atomicAdd(&wcur[(r.x >> 24) & 31], 1);
        stag[pos] = make_int2((r.x & 0xFFFFFF) << 7, r.y);
    }
    __syncthreads();

    const int wave = tid >> 6, lane = tid & 63;
    const int g = lane >> 4;              // edge slot 0..3
    const int c4 = (lane & 15) * 4;       // channel base within the 64-ch half
    const int c4b = c4 * 2;               // ...as bytes

#define ACC2(q, w) {                                                        \
        unsigned ux = (unsigned)(q).x, uy = (unsigned)(q).y;                \
        f32x2 ww; ww[0] = (w); ww[1] = (w);                                 \
        f32x2 v01, v23;                                                     \
        v01[0] = __uint_as_float(ux << 16);                                 \
        v01[1] = __uint_as_float(ux & 0xFFFF0000u);                         \
        v23[0] = __uint_as_float(uy << 16);                                 \
        v23[1] = __uint_as_float(uy & 0xFFFF0000u);                         \
        a01 = v01 * ww + a01; a23 = v23 * ww + a23; }

#pragma unroll
    for (int hh = 0; hh < 2; ++hh) {
        const char* hb = (const char*)h + ((size_t)hh * (size_t)N << 7);
        for (int nl = wave; nl < PS; nl += 4) {
            int n = p * PS + nl;
            if (n >= N) continue;
            const int s = cstart[nl], e = cstart[nl + 1];
            f32x2 a01 = {0.f, 0.f}, a23 = {0.f, 0.f};
            int j = s;
            const int e32 = s + ((e - s) & ~31);
            for (; j < e32; j += 32) {
                int2 r0 = stag[j + g];
                int2 r1 = stag[j + 4 + g];
                int2 r2 = stag[j + 8 + g];
                int2 r3 = stag[j + 12 + g];
                int2 r4 = stag[j + 16 + g];
                int2 r5 = stag[j + 20 + g];
                int2 r6 = stag[j + 24 + g];
                int2 r7 = stag[j + 28 + g];
                int2 q0 = *(const int2*)(hb + ((unsigned)r0.x + c4b));
                int2 q1 = *(const int2*)(hb + ((unsigned)r1.x + c4b));
                int2 q2 = *(const int2*)(hb + ((unsigned)r2.x + c4b));
                int2 q3 = *(const int2*)(hb + ((unsigned)r3.x + c4b));
                int2 q4 = *(const int2*)(hb + ((unsigned)r4.x + c4b));
                int2 q5 = *(const int2*)(hb + ((unsigned)r5.x + c4b));
                int2 q6 = *(const int2*)(hb + ((unsigned)r6.x + c4b));
                int2 q7 = *(const int2*)(hb + ((unsigned)r7.x + c4b));
                ACC2(q0, __int_as_float(r0.y));
                ACC2(q1, __int_as_float(r1.y));
                ACC2(q2, __int_as_float(r2.y));
                ACC2(q3, __int_as_float(r3.y));
                ACC2(q4, __int_as_float(r4.y));
                ACC2(q5, __int_as_float(r5.y));
                ACC2(q6, __int_as_float(r6.y));
                ACC2(q7, __int_as_float(r7.y));
            }
            const int e16 = s + ((e - s) & ~15);
            for (; j < e16; j += 16) {
                int2 r0 = stag[j + g];
                int2 r1 = stag[j + 4 + g];
                int2 r2 = stag[j + 8 + g];
                int2 r3 = stag[j + 12 + g];
                int2 q0 = *(const int2*)(hb + ((unsigned)r0.x + c4b));
                int2 q1 = *(const int2*)(hb + ((unsigned)r1.x + c4b));
                int2 q2 = *(const int2*)(hb + ((unsigned)r2.x + c4b));
                int2 q3 = *(const int2*)(hb + ((unsigned)r3.x + c4b));
                ACC2(q0, __int_as_float(r0.y));
                ACC2(q1, __int_as_float(r1.y));
                ACC2(q2, __int_as_float(r2.y));
                ACC2(q3, __int_as_float(r3.y));
            }
            for (; j < e; j += 8) {
                int j0 = j + g, j1 = j + 4 + g;
                int2 r0 = stag[j0 < e ? j0 : s];
                int2 r1 = stag[j1 < e ? j1 : s];
                float w0 = (j0 < e) ? __int_as_float(r0.y) : 0.f;
                float w1 = (j1 < e) ? __int_as_float(r1.y) : 0.f;
                int2 q0 = *(const int2*)(hb + ((unsigned)r0.x + c4b));
                int2 q1 = *(const int2*)(hb + ((unsigned)r1.x + c4b));
                ACC2(q0, w0);
                ACC2(q1, w1);
            }
            float acc[4] = {a01[0], a01[1], a23[0], a23[1]};
#pragma unroll
            for (int k = 0; k < 4; ++k) {
                float v = acc[k];
                v += __shfl_xor(v, 16, 64);
                v += __shfl_xor(v, 32, 64);
                acc[k] = v;
            }
            if (g == 0) {
                float di = dinv[n];
                int2 qs = *(const int2*)(hb + (((size_t)(unsigned)n << 7) + c4b));
                float4 b = *(const float4*)(bconv + hh * 64 + c4);
                unsigned ux = (unsigned)qs.x, uy = (unsigned)qs.y;
                bf16x4 o;
                o[0] = (short)f2bf(fmaxf(di * (acc[0] + __uint_as_float(ux << 16)) + b.x, 0.f));
                o[1] = (short)f2bf(fmaxf(di * (acc[1] + __uint_as_float(ux & 0xFFFF0000u)) + b.y, 0.f));
                o[2] = (short)f2bf(fmaxf(di * (acc[2] + __uint_as_float(uy << 16)) + b.z, 0.f));
                o[3] = (short)f2bf(fmaxf(di * (acc[3] + __uint_as_float(uy & 0xFFFF0000u)) + b.w, 0.f));
                *(bf16x4*)(h2 + (size_t)n * 128 + hh * 64 + c4) = o;
            }
        }
    }
#undef ACC2
}

// ---- gemm23: out = relu(h2 @ Wf^T + bf) @ W2^T + b2, intermediate staged in LDS ----
__global__ __launch_bounds__(256) void gemm23_k(const unsigned short* __restrict__ h2,
                                                const unsigned short* __restrict__ Wfb,
                                                const float* __restrict__ bfc,
                                                const unsigned short* __restrict__ W2b,
                                                const float* __restrict__ b2,
                                                float* __restrict__ out, int M) {
    __shared__ __align__(16) unsigned short Wl[128 * 136];
    __shared__ __align__(16) unsigned short Tl[64 * 136];
    const int tid = threadIdx.x;

    // stage Wfb (bf16 dense) -> Wl (136-stride)
#pragma unroll
    for (int i = 0; i < 8; ++i) {
        int c = i * 256 + tid;
        int r = c >> 4, col = (c & 15) * 8;
        *(bf16x8*)&Wl[r * 136 + col] = *(const bf16x8*)(Wfb + c * 8);
    }
    __syncthreads();

    const int wave = tid >> 6, lane = tid & 63;
    const int m = lane & 15, quad = lane >> 4;
    const int rowBase = blockIdx.x * 64 + wave * 16;
    int arow = rowBase + m;
    int arowc = arow < M ? arow : (M - 1);

    bf16x8 afrag[4];
    {
        const unsigned short* pa = h2 + (size_t)arowc * 128 + quad * 8;
#pragma unroll
        for (int kc = 0; kc < 4; ++kc)
            afrag[kc] = *(const bf16x8*)(pa + kc * 32);
    }

    // stage 1: T = bf16(relu(h2 @ Wf^T + bf)) -> LDS
#pragma unroll
    for (int nt = 0; nt < 8; ++nt) {
        f32x4 acc = {0.f, 0.f, 0.f, 0.f};
        const unsigned short* wb = &Wl[(nt * 16 + m) * 136 + quad * 8];
#pragma unroll
        for (int kc = 0; kc < 4; ++kc) {
            bf16x8 bfrag = *(const bf16x8*)(wb + kc * 32);
            acc = __builtin_amdgcn_mfma_f32_16x16x32_bf16(afrag[kc], bfrag, acc, 0, 0, 0);
        }
        const int col = nt * 16 + m;
        float bv = bfc[col];
#pragma unroll
        for (int r = 0; r < 4; ++r) {
            int rowl = wave * 16 + quad * 4 + r;
            Tl[rowl * 136 + col] = f2bf(fmaxf(acc[r] + bv, 0.f));
        }
    }
    __syncthreads();

    // stage W2b (overwrite Wl)
#pragma unroll
    for (int i = 0; i < 8; ++i) {
        int c = i * 256 + tid;
        int r = c >> 4, col = (c & 15) * 8;
        *(bf16x8*)&Wl[r * 136 + col] = *(const bf16x8*)(W2b + c * 8);
    }
    __syncthreads();

    // stage 2: out = T @ W2^T + b2
    bf16x8 afrag2[4];
    {
        const unsigned short* pa = &Tl[(wave * 16 + m) * 136 + quad * 8];
#pragma unroll
        for (int kc = 0; kc < 4; ++kc)
            afrag2[kc] = *(const bf16x8*)(pa + kc * 32);
    }
#pragma unroll
    for (int nt = 0; nt < 8; ++nt) {
        f32x4 acc = {0.f, 0.f, 0.f, 0.f};
        const unsigned short* wb = &Wl[(nt * 16 + m) * 136 + quad * 8];
#pragma unroll
        for (int kc = 0; kc < 4; ++kc) {
            bf16x8 bfrag = *(const bf16x8*)(wb + kc * 32);
            acc = __builtin_amdgcn_mfma_f32_16x16x32_bf16(afrag2[kc], bfrag, acc, 0, 0, 0);
        }
        const int col = nt * 16 + m;
        float bv = b2[col];
#pragma unroll
        for (int r = 0; r < 4; ++r) {
            int row = rowBase + quad * 4 + r;
            if (row < M)
                out[(size_t)row * 128 + col] = acc[r] + bv;
        }
    }
}

extern "C" void kernel_launch(void* const* d_in, const int* in_sizes, int n_in,
                              void* d_out, int out_size, void* d_ws, size_t ws_size,
                              hipStream_t stream) {
    const float* x  = (const float*)d_in[0];
    const int* ei   = (const int*)d_in[1];
    const float* ew = (const float*)d_in[2];
    const float* Wc = (const float*)d_in[3];
    const float* bc = (const float*)d_in[4];
    const float* Wf = (const float*)d_in[5];
    const float* bf = (const float*)d_in[6];
    const float* W2 = (const float*)d_in[7];
    const float* b2 = (const float*)d_in[8];
    float* out = (float*)d_out;

    const int N = in_sizes[0] / 128;
    const int E = in_sizes[2];
    const int P = (N + PS - 1) / PS;     // 3125
    const int NBK = (N + 511) >> 9;      // 196 buckets of 16 partitions

    auto align256 = [](size_t v) { return (v + 255) & ~(size_t)255; };
    char* ws = (char*)d_ws;
    size_t off = 0;
    float* dinv  = (float*)(ws + off); off += align256((size_t)N * 4);
    int* nodeOff = (int*)(ws + off);   off += align256((size_t)N * 4);
    int* partCnt = (int*)(ws + off);   off += align256((size_t)P * 4);
    int* bucketCnt = (int*)(ws + off); off += align256((size_t)NBK * 4);
    unsigned short* wcb = (unsigned short*)(ws + off); off += align256(16384 * 2);
    unsigned short* wfb = (unsigned short*)(ws + off); off += align256(16384 * 2);
    unsigned short* w2b = (unsigned short*)(ws + off); off += align256(16384 * 2);
    unsigned short* h  = (unsigned short*)(ws + off); off += (size_t)N * 256;  // h'[2][N][64] channel-split
    unsigned short* h2 = (unsigned short*)(ws + off);

    // bstage (NBK*CAPB*8B = 27.5MB) aliases [h, h2]: dead before dgemm1 writes h.
    int2* bstage = (int2*)h;

    // d_out scratch: partition regions P*CAPP*8B = 32.8MB <= 51.2MB,
    // consumed by aggF before gemm23 rewrites d_out.
    int2* regions = (int2*)out;

    const int EPB = (E + NB - 1) / NB;

    hipMemsetAsync(bucketCnt, 0, (size_t)NBK * 4, stream);
    scatA_k<<<NB, 1024, 0, stream>>>(ei, ew, bucketCnt, bstage, Wc, Wf, W2, wcb, wfb, w2b, E, NBK, EPB);
    scatB_k<<<NBK, 1024, 0, stream>>>(bucketCnt, bstage, partCnt, regions, P);
    dgemm1_k<<<(N + 63) / 64, 256, 0, stream>>>(x, wcb, partCnt, regions, dinv, nodeOff, h, N, P);
    aggF_k<<<P, 256, 0, stream>>>(partCnt, nodeOff, regions, h, dinv, bc, h2, N);
    gemm23_k<<<(N + 63) / 64, 256, 0, stream>>>(h2, wfb, bf, w2b, b2, out, N);
}